// Round 2
// baseline (1752.144 us; speedup 1.0000x reference)
//
#include <hip/hip_runtime.h>

typedef short  short8  __attribute__((ext_vector_type(8)));
typedef float  float4v __attribute__((ext_vector_type(4)));

#define DIM      1024
#define HEADS    16
#define HEAD_DIM 64
#define HIDDEN   4096
#define BATCH    16
#define SEQ      577
#define M_ROWS   (BATCH*SEQ)   /* 9232 */
#define NPAD     608           /* 577 padded to 19*32 */

static __device__ __forceinline__ unsigned short f2bf(float f) {
  unsigned int u = __float_as_uint(f);
  u += 0x7FFFu + ((u >> 16) & 1u);           // round-to-nearest-even
  return (unsigned short)(u >> 16);
}
static __device__ __forceinline__ float bf2f(unsigned short h) {
  return __uint_as_float(((unsigned int)h) << 16);
}

// ---------------------------------------------------------------- fp32 -> bf16
__global__ __launch_bounds__(256) void f32_to_bf16_kernel(
    const float* __restrict__ in, unsigned short* __restrict__ out, int n4) {
  int i = blockIdx.x * 256 + threadIdx.x;
  if (i >= n4) return;
  float4 v = ((const float4*)in)[i];
  union { unsigned short s[4]; uint2 u; } p;
  p.s[0] = f2bf(v.x); p.s[1] = f2bf(v.y); p.s[2] = f2bf(v.z); p.s[3] = f2bf(v.w);
  ((uint2*)out)[i] = p.u;
}

// ---------------------------------------------------------------- LayerNorm row
// one block per row, C = 1024, 256 threads * float4
__global__ __launch_bounds__(256) void ln_kernel(
    const float* __restrict__ x, const float* __restrict__ g,
    const float* __restrict__ b, unsigned short* __restrict__ out) {
  int row = blockIdx.x, tid = threadIdx.x;
  const float* xr = x + (long long)row * DIM;
  float4 v = *(const float4*)(xr + tid * 4);
  float s1 = v.x + v.y + v.z + v.w;
  float s2 = v.x*v.x + v.y*v.y + v.z*v.z + v.w*v.w;
  for (int o = 32; o; o >>= 1) { s1 += __shfl_xor(s1, o); s2 += __shfl_xor(s2, o); }
  __shared__ float a1[4], a2[4];
  int wid = tid >> 6, lane = tid & 63;
  if (lane == 0) { a1[wid] = s1; a2[wid] = s2; }
  __syncthreads();
  s1 = a1[0] + a1[1] + a1[2] + a1[3];
  s2 = a2[0] + a2[1] + a2[2] + a2[3];
  float mean = s1 * (1.f / DIM);
  float var  = s2 * (1.f / DIM) - mean * mean;
  float rstd = rsqrtf(var + 1e-5f);
  float4 gv = *(const float4*)(g + tid * 4);
  float4 bv = *(const float4*)(b + tid * 4);
  union { unsigned short s[4]; uint2 u; } p;
  p.s[0] = f2bf((v.x - mean) * rstd * gv.x + bv.x);
  p.s[1] = f2bf((v.y - mean) * rstd * gv.y + bv.y);
  p.s[2] = f2bf((v.z - mean) * rstd * gv.z + bv.z);
  p.s[3] = f2bf((v.w - mean) * rstd * gv.w + bv.w);
  *(uint2*)(out + (long long)row * DIM + tid * 4) = p.u;
}

// ---------------------------------------------------------------- V transpose
// vt[bh][d][n] (ld NPAD, zero-padded n>=577)  <-  v[(b*577+n)*1024 + h*64 + d]
__global__ __launch_bounds__(256) void transpose_v_kernel(
    const unsigned short* __restrict__ v, unsigned short* __restrict__ vt) {
  int t = blockIdx.x * 256 + threadIdx.x;          // exactly 256*64*76 threads
  int chunk = t % 76;
  int rest  = t / 76;
  int d  = rest & 63;
  int bh = rest >> 6;
  int b = bh >> 4, h = bh & 15;
  union { unsigned short s[8]; uint4 u; } p;
  for (int i = 0; i < 8; i++) {
    int n = chunk * 8 + i;
    p.s[i] = (n < SEQ) ? v[((long long)(b * SEQ + n)) * DIM + h * HEAD_DIM + d] : (unsigned short)0;
  }
  *(uint4*)(vt + ((long long)bh * HEAD_DIM + d) * NPAD + chunk * 8) = p.u;
}

// ---------------------------------------------------------------- row softmax
// in-place on S chunk (bf16), ld = NPAD; one wave per row; grid = rows/4
__global__ __launch_bounds__(256) void softmax_kernel(unsigned short* __restrict__ S) {
  int lane = threadIdx.x & 63;
  int row  = blockIdx.x * 4 + (threadIdx.x >> 6);
  unsigned short* r = S + (long long)row * NPAD;
  float s[10];
  float m = -1e30f;
  for (int j = 0; j < 10; j++) {
    int col = j * 64 + lane;
    s[j] = (col < SEQ) ? bf2f(r[col]) : -1e30f;
    m = fmaxf(m, s[j]);
  }
  for (int o = 32; o; o >>= 1) m = fmaxf(m, __shfl_xor(m, o));
  float sum = 0.f;
  for (int j = 0; j < 10; j++) {
    int col = j * 64 + lane;
    float e = (col < SEQ) ? __expf(s[j] - m) : 0.f;
    s[j] = e; sum += e;
  }
  for (int o = 32; o; o >>= 1) sum += __shfl_xor(sum, o);
  float inv = 1.f / sum;
  for (int j = 0; j < 10; j++) {
    int col = j * 64 + lane;
    if (col < NPAD) r[col] = (col < SEQ) ? f2bf(s[j] * inv) : (unsigned short)0;
  }
}

// ---------------------------------------------------------------- NT GEMM
// C[M,N] = A[M,K] (row-major, bf16) * B[N,K]^T (row-major, bf16)
// block 128x128, 4 waves 2x2, each wave 64x64 via 4x4 mfma 16x16x32
enum { EPI_BF16 = 0, EPI_SCALE_BF16 = 1, EPI_BIAS_RES_F32 = 2, EPI_BIAS_GELU_BF16 = 3 };

template <int EPI>
__global__ __launch_bounds__(256) void gemm_nt(
    const unsigned short* __restrict__ A, int lda, long long sAb, long long sAh,
    const unsigned short* __restrict__ B, int ldb, long long sBb, long long sBh,
    void* __restrict__ Cout, int ldc, long long sCb, long long sCh,
    const float* __restrict__ bias, const float* __restrict__ res,
    int M, int N, int K, float scale) {
  int bh = blockIdx.z;
  int bb = bh >> 4, hh = bh & 15;
  A += bb * sAb + hh * sAh;
  B += bb * sBb + hh * sBh;
  long long cOff = bb * sCb + hh * sCh;

  int m0 = blockIdx.x * 128, n0 = blockIdx.y * 128;
  int tid = threadIdx.x;
  int lane = tid & 63, wid = tid >> 6;
  int wm = wid >> 1, wn = wid & 1;
  int quad = lane >> 4, l16 = lane & 15;

  __shared__ __align__(16) unsigned short As[128][40];  // row stride 80 B (16B-multiple), 2-way bank aliasing only
  __shared__ __align__(16) unsigned short Bs[128][40];

  float4v acc[4][4];
  for (int i = 0; i < 4; i++)
    for (int j = 0; j < 4; j++) acc[i][j] = (float4v){0.f, 0.f, 0.f, 0.f};

  int lrow = tid >> 2;   // 0..63
  int lc   = tid & 3;    // 16B chunk

  for (int k0 = 0; k0 < K; k0 += 32) {
    for (int p = 0; p < 2; p++) {
      int r = lrow + p * 64;
      int gr = m0 + r; if (gr > M - 1) gr = M - 1;           // clamp; stores guarded
      uint4 va = *(const uint4*)(A + (long long)gr * lda + k0 + lc * 8);
      *(uint4*)(&As[r][lc * 8]) = va;
      int gn = n0 + r; if (gn > N - 1) gn = N - 1;
      uint4 vb = *(const uint4*)(B + (long long)gn * ldb + k0 + lc * 8);
      *(uint4*)(&Bs[r][lc * 8]) = vb;
    }
    __syncthreads();
    short8 af[4], bfr[4];
    for (int i = 0; i < 4; i++) af[i]  = *(const short8*)(&As[wm * 64 + i * 16 + l16][quad * 8]);
    for (int j = 0; j < 4; j++) bfr[j] = *(const short8*)(&Bs[wn * 64 + j * 16 + l16][quad * 8]);
    for (int i = 0; i < 4; i++)
      for (int j = 0; j < 4; j++)
        acc[i][j] = __builtin_amdgcn_mfma_f32_16x16x32_bf16(af[i], bfr[j], acc[i][j], 0, 0, 0);
    __syncthreads();
  }

  // epilogue: C/D layout col = lane&15, row = quad*4 + reg  [m89-verified]
  for (int i = 0; i < 4; i++) {
    int rowb = m0 + wm * 64 + i * 16 + quad * 4;
    for (int j = 0; j < 4; j++) {
      int col = n0 + wn * 64 + j * 16 + l16;
      if (col >= N) continue;
      for (int r = 0; r < 4; r++) {
        int rr = rowb + r;
        if (rr >= M) continue;
        float v = acc[i][j][r];
        long long idx = cOff + (long long)rr * ldc + col;
        if constexpr (EPI == EPI_BF16) {
          ((unsigned short*)Cout)[idx] = f2bf(v);
        } else if constexpr (EPI == EPI_SCALE_BF16) {
          ((unsigned short*)Cout)[idx] = f2bf(v * scale);
        } else if constexpr (EPI == EPI_BIAS_RES_F32) {
          ((float*)Cout)[idx] = v + bias[col] + res[(long long)rr * ldc + col];
        } else if constexpr (EPI == EPI_BIAS_GELU_BF16) {
          float t = v + bias[col];
          t = t / (1.f + __expf(-1.702f * t));        // fast_gelu = x*sigmoid(1.702x)
          ((unsigned short*)Cout)[idx] = f2bf(t);
        }
      }
    }
  }
}

// ----------------------------------------------------------------------------
extern "C" void kernel_launch(void* const* d_in, const int* in_sizes, int n_in,
                              void* d_out, int out_size, void* d_ws, size_t ws_size,
                              hipStream_t stream) {
  const float* x   = (const float*)d_in[0];
  const float* g1  = (const float*)d_in[1];
  const float* be1 = (const float*)d_in[2];
  const float* Wq  = (const float*)d_in[3];
  const float* Wk  = (const float*)d_in[4];
  const float* Wv  = (const float*)d_in[5];
  const float* Wp  = (const float*)d_in[6];
  const float* bp  = (const float*)d_in[7];
  const float* g2  = (const float*)d_in[8];
  const float* be2 = (const float*)d_in[9];
  const float* W1  = (const float*)d_in[10];
  const float* b1  = (const float*)d_in[11];
  const float* W2  = (const float*)d_in[12];
  const float* b2  = (const float*)d_in[13];
  float* out = (float*)d_out;

  // ---- workspace layout (lean: ~126..158 MB depending on chunk G) ----
  char* ws = (char*)d_ws;
  size_t off = 0;
  auto alloc = [&](size_t bytes) {
    size_t r = off; off += (bytes + 255) & ~(size_t)255; return r;
  };
  unsigned short* wq_bf = (unsigned short*)(ws + alloc((size_t)DIM * DIM * 2));
  unsigned short* wk_bf = (unsigned short*)(ws + alloc((size_t)DIM * DIM * 2));
  unsigned short* wv_bf = (unsigned short*)(ws + alloc((size_t)DIM * DIM * 2));
  unsigned short* wp_bf = (unsigned short*)(ws + alloc((size_t)DIM * DIM * 2));
  unsigned short* w1_bf = (unsigned short*)(ws + alloc((size_t)HIDDEN * DIM * 2));
  unsigned short* w2_bf = (unsigned short*)(ws + alloc((size_t)HIDDEN * DIM * 2));
  unsigned short* h_bf  = (unsigned short*)(ws + alloc((size_t)M_ROWS * DIM * 2));  // ln1 out; later o; later ln2 out
  unsigned short* q_bf  = (unsigned short*)(ws + alloc((size_t)M_ROWS * DIM * 2));
  unsigned short* k_bf  = (unsigned short*)(ws + alloc((size_t)M_ROWS * DIM * 2));
  unsigned short* v_bf  = (unsigned short*)(ws + alloc((size_t)M_ROWS * DIM * 2));
  unsigned short* vt_bf = (unsigned short*)(ws + alloc((size_t)256 * HEAD_DIM * NPAD * 2));
  size_t base_end = off;

  // attention score chunk: G heads at a time, G in {64,32,16}, largest that fits
  int G = 64;
  while (G > 16 && base_end + (((size_t)G * SEQ * NPAD * 2 + 255) & ~(size_t)255) > ws_size)
    G >>= 1;
  unsigned short* S_bf = (unsigned short*)(ws + alloc((size_t)G * SEQ * NPAD * 2));

  // aliases (all producers/consumers strictly ordered on `stream`):
  unsigned short* o_bf  = h_bf;   // o written after h (ln1 out) is dead
  unsigned short* h2_bf = h_bf;   // ln2 out written after o consumed
  unsigned short* u_bf  = q_bf;   // MLP hidden (75.6 MB) over dead [q|k|v|vt] span (76.6 MB)
  float*          x1    = out;    // residual-1 result lives in d_out (exact size match)

  // 1. weights fp32 -> bf16
  f32_to_bf16_kernel<<<(DIM * DIM / 4 + 255) / 256, 256, 0, stream>>>(Wq, wq_bf, DIM * DIM / 4);
  f32_to_bf16_kernel<<<(DIM * DIM / 4 + 255) / 256, 256, 0, stream>>>(Wk, wk_bf, DIM * DIM / 4);
  f32_to_bf16_kernel<<<(DIM * DIM / 4 + 255) / 256, 256, 0, stream>>>(Wv, wv_bf, DIM * DIM / 4);
  f32_to_bf16_kernel<<<(DIM * DIM / 4 + 255) / 256, 256, 0, stream>>>(Wp, wp_bf, DIM * DIM / 4);
  f32_to_bf16_kernel<<<(HIDDEN * DIM / 4 + 255) / 256, 256, 0, stream>>>(W1, w1_bf, HIDDEN * DIM / 4);
  f32_to_bf16_kernel<<<(HIDDEN * DIM / 4 + 255) / 256, 256, 0, stream>>>(W2, w2_bf, HIDDEN * DIM / 4);

  // 2. h = LN1(x)
  ln_kernel<<<M_ROWS, 256, 0, stream>>>(x, g1, be1, h_bf);

  // 3. q/k/v = h @ W{q,k,v}^T
  dim3 gQKV(73, 8, 1);
  gemm_nt<EPI_BF16><<<gQKV, 256, 0, stream>>>(h_bf, DIM, 0, 0, wq_bf, DIM, 0, 0,
      q_bf, DIM, 0, 0, nullptr, nullptr, M_ROWS, DIM, DIM, 1.f);
  gemm_nt<EPI_BF16><<<gQKV, 256, 0, stream>>>(h_bf, DIM, 0, 0, wk_bf, DIM, 0, 0,
      k_bf, DIM, 0, 0, nullptr, nullptr, M_ROWS, DIM, DIM, 1.f);
  gemm_nt<EPI_BF16><<<gQKV, 256, 0, stream>>>(h_bf, DIM, 0, 0, wv_bf, DIM, 0, 0,
      v_bf, DIM, 0, 0, nullptr, nullptr, M_ROWS, DIM, DIM, 1.f);

  // 4. vt[bh][d][n]  (v dead afterwards)
  transpose_v_kernel<<<256 * HEAD_DIM * (NPAD / 8) / 256, 256, 0, stream>>>(v_bf, vt_bf);

  // 5-7. attention, chunked over G heads (bh = g..g+G-1); G multiple of 16
  for (int g = 0; g < 256; g += G) {
    int bb0 = g >> 4;
    // S = (Q K^T) * scale
    gemm_nt<EPI_SCALE_BF16><<<dim3(5, 5, G), 256, 0, stream>>>(
        q_bf + (size_t)bb0 * SEQ * DIM, DIM, (long long)SEQ * DIM, HEAD_DIM,
        k_bf + (size_t)bb0 * SEQ * DIM, DIM, (long long)SEQ * DIM, HEAD_DIM,
        S_bf, NPAD, 16LL * SEQ * NPAD, (long long)SEQ * NPAD,
        nullptr, nullptr, SEQ, SEQ, HEAD_DIM, 0.125f);
    // P = softmax(S) in-place (zeros the key-pad cols)
    softmax_kernel<<<G * SEQ / 4, 256, 0, stream>>>(S_bf);
    // O = P @ V  (NT against vt, K-dim = NPAD)
    gemm_nt<EPI_BF16><<<dim3(5, 1, G), 256, 0, stream>>>(
        S_bf, NPAD, 16LL * SEQ * NPAD, (long long)SEQ * NPAD,
        vt_bf + (size_t)g * HEAD_DIM * NPAD, NPAD, 16LL * HEAD_DIM * NPAD, (long long)HEAD_DIM * NPAD,
        o_bf + (size_t)bb0 * SEQ * DIM, DIM, (long long)SEQ * DIM, HEAD_DIM,
        nullptr, nullptr, SEQ, HEAD_DIM, NPAD, 1.f);
  }

  // 8. x1 = x + O @ Wp^T + bp   (x1 lives in d_out)
  gemm_nt<EPI_BIAS_RES_F32><<<gQKV, 256, 0, stream>>>(o_bf, DIM, 0, 0, wp_bf, DIM, 0, 0,
      x1, DIM, 0, 0, bp, x, M_ROWS, DIM, DIM, 1.f);

  // 9. h2 = LN2(x1)   (overwrites o storage — o already consumed)
  ln_kernel<<<M_ROWS, 256, 0, stream>>>(x1, g2, be2, h2_bf);

  // 10. u = fast_gelu(h2 @ W1^T + b1)   (u over dead q/k/v/vt span)
  dim3 gM1(73, 32, 1);
  gemm_nt<EPI_BIAS_GELU_BF16><<<gM1, 256, 0, stream>>>(h2_bf, DIM, 0, 0, w1_bf, DIM, 0, 0,
      u_bf, HIDDEN, 0, 0, b1, nullptr, M_ROWS, HIDDEN, DIM, 1.f);

  // 11. out = x1 + u @ W2^T + b2   (res read + write same element in same thread — safe)
  gemm_nt<EPI_BIAS_RES_F32><<<gQKV, 256, 0, stream>>>(u_bf, HIDDEN, 0, 0, w2_bf, HIDDEN, 0, 0,
      out, DIM, 0, 0, b2, x1, M_ROWS, DIM, HIDDEN, 1.f);
}

// Round 3
// 868.563 us; speedup vs baseline: 2.0173x; 2.0173x over previous
//
#include <hip/hip_runtime.h>

typedef short  short8  __attribute__((ext_vector_type(8)));
typedef float  float4v __attribute__((ext_vector_type(4)));

#define DIM      1024
#define HEADS    16
#define HEAD_DIM 64
#define HIDDEN   4096
#define BATCH    16
#define SEQ      577
#define M_ROWS   (BATCH*SEQ)   /* 9232 */
#define NPAD     608           /* 577 padded to 19*32 */
#define LOG2E    1.4426950408889634f

static __device__ __forceinline__ unsigned short f2bf(float f) {
  unsigned int u = __float_as_uint(f);
  u += 0x7FFFu + ((u >> 16) & 1u);           // round-to-nearest-even
  return (unsigned short)(u >> 16);
}
static __device__ __forceinline__ float bf2f(unsigned short h) {
  return __uint_as_float(((unsigned int)h) << 16);
}

// ---------------------------------------------------------------- fp32 -> bf16
__global__ __launch_bounds__(256) void f32_to_bf16_kernel(
    const float* __restrict__ in, unsigned short* __restrict__ out, int n4) {
  int i = blockIdx.x * 256 + threadIdx.x;
  if (i >= n4) return;
  float4 v = ((const float4*)in)[i];
  union { unsigned short s[4]; uint2 u; } p;
  p.s[0] = f2bf(v.x); p.s[1] = f2bf(v.y); p.s[2] = f2bf(v.z); p.s[3] = f2bf(v.w);
  ((uint2*)out)[i] = p.u;
}

// ---------------------------------------------------------------- LayerNorm row
__global__ __launch_bounds__(256) void ln_kernel(
    const float* __restrict__ x, const float* __restrict__ g,
    const float* __restrict__ b, unsigned short* __restrict__ out) {
  int row = blockIdx.x, tid = threadIdx.x;
  const float* xr = x + (long long)row * DIM;
  float4 v = *(const float4*)(xr + tid * 4);
  float s1 = v.x + v.y + v.z + v.w;
  float s2 = v.x*v.x + v.y*v.y + v.z*v.z + v.w*v.w;
  #pragma unroll
  for (int o = 32; o; o >>= 1) { s1 += __shfl_xor(s1, o); s2 += __shfl_xor(s2, o); }
  __shared__ float a1[4], a2[4];
  int wid = tid >> 6, lane = tid & 63;
  if (lane == 0) { a1[wid] = s1; a2[wid] = s2; }
  __syncthreads();
  s1 = a1[0] + a1[1] + a1[2] + a1[3];
  s2 = a2[0] + a2[1] + a2[2] + a2[3];
  float mean = s1 * (1.f / DIM);
  float var  = s2 * (1.f / DIM) - mean * mean;
  float rstd = rsqrtf(var + 1e-5f);
  float4 gv = *(const float4*)(g + tid * 4);
  float4 bv = *(const float4*)(b + tid * 4);
  union { unsigned short s[4]; uint2 u; } p;
  p.s[0] = f2bf((v.x - mean) * rstd * gv.x + bv.x);
  p.s[1] = f2bf((v.y - mean) * rstd * gv.y + bv.y);
  p.s[2] = f2bf((v.z - mean) * rstd * gv.z + bv.z);
  p.s[3] = f2bf((v.w - mean) * rstd * gv.w + bv.w);
  *(uint2*)(out + (long long)row * DIM + tid * 4) = p.u;
}

// ---------------------------------------------------------------- V transpose
__global__ __launch_bounds__(256) void transpose_v_kernel(
    const unsigned short* __restrict__ v, unsigned short* __restrict__ vt) {
  int t = blockIdx.x * 256 + threadIdx.x;          // exactly 256*64*76 threads
  int chunk = t % 76;
  int rest  = t / 76;
  int d  = rest & 63;
  int bh = rest >> 6;
  int b = bh >> 4, h = bh & 15;
  union { unsigned short s[8]; uint4 u; } p;
  #pragma unroll
  for (int i = 0; i < 8; i++) {
    int n = chunk * 8 + i;
    p.s[i] = (n < SEQ) ? v[((long long)(b * SEQ + n)) * DIM + h * HEAD_DIM + d] : (unsigned short)0;
  }
  *(uint4*)(vt + ((long long)bh * HEAD_DIM + d) * NPAD + chunk * 8) = p.u;
}

// ---------------------------------------------------------------- row softmax
__global__ __launch_bounds__(256) void softmax_kernel(unsigned short* __restrict__ S) {
  int lane = threadIdx.x & 63;
  int row  = blockIdx.x * 4 + (threadIdx.x >> 6);
  unsigned short* r = S + (long long)row * NPAD;
  float s[10];
  float m = -1e30f;
  #pragma unroll
  for (int j = 0; j < 10; j++) {
    int col = j * 64 + lane;
    s[j] = (col < SEQ) ? bf2f(r[col]) : -1e30f;
    m = fmaxf(m, s[j]);
  }
  #pragma unroll
  for (int o = 32; o; o >>= 1) m = fmaxf(m, __shfl_xor(m, o));
  float sum = 0.f;
  #pragma unroll
  for (int j = 0; j < 10; j++) {
    int col = j * 64 + lane;
    float e = (col < SEQ) ? __builtin_amdgcn_exp2f((s[j] - m) * LOG2E) : 0.f;
    s[j] = e; sum += e;
  }
  #pragma unroll
  for (int o = 32; o; o >>= 1) sum += __shfl_xor(sum, o);
  float inv = 1.f / sum;
  #pragma unroll
  for (int j = 0; j < 10; j++) {
    int col = j * 64 + lane;
    if (col < NPAD) r[col] = (col < SEQ) ? f2bf(s[j] * inv) : (unsigned short)0;
  }
}

// ---------------------------------------------------------------- NT GEMM
// C[M,N] = A[M,K] (row-major, bf16) * B[N,K]^T (row-major, bf16)
// block 128x128, 4 waves 2x2, each wave 64x64 via 4x4 mfma 16x16x32
// Epilogue stages the wave's C-tile through LDS for coalesced vector stores
// and tiny live state (anti-spill: R2 showed 4.8 GB scratch writes in the
// GELU instantiation).
enum { EPI_BF16 = 0, EPI_SCALE_BF16 = 1, EPI_BIAS_RES_F32 = 2, EPI_BIAS_GELU_BF16 = 3 };

template <int EPI>
__global__ __launch_bounds__(256, 2) void gemm_nt(
    const unsigned short* __restrict__ A, int lda, long long sAb, long long sAh,
    const unsigned short* __restrict__ B, int ldb, long long sBb, long long sBh,
    void* __restrict__ Cout, int ldc, long long sCb, long long sCh,
    const float* __restrict__ bias, const float* __restrict__ res,
    int M, int N, int K, float scale) {
  int bh = blockIdx.z;
  int bb = bh >> 4, hh = bh & 15;
  A += bb * sAb + hh * sAh;
  B += bb * sBb + hh * sBh;
  long long cOff = bb * sCb + hh * sCh;

  int m0 = blockIdx.x * 128, n0 = blockIdx.y * 128;
  int tid = threadIdx.x;
  int lane = tid & 63, wid = tid >> 6;
  int wm = wid >> 1, wn = wid & 1;
  int quad = lane >> 4, l16 = lane & 15;

  // [0]=A tile, [1]=B tile; epilogue reuses the whole span as fp32 scratch
  __shared__ __align__(16) unsigned short SM[2][128][40];

  float4v acc[4][4];
  #pragma unroll
  for (int i = 0; i < 4; i++)
    #pragma unroll
    for (int j = 0; j < 4; j++) acc[i][j] = (float4v){0.f, 0.f, 0.f, 0.f};

  int lrow = tid >> 2;   // 0..63
  int lc   = tid & 3;    // 16B chunk

  for (int k0 = 0; k0 < K; k0 += 32) {
    #pragma unroll
    for (int p = 0; p < 2; p++) {
      int r = lrow + p * 64;
      int gr = m0 + r; if (gr > M - 1) gr = M - 1;           // clamp; stores guarded
      uint4 va = *(const uint4*)(A + (long long)gr * lda + k0 + lc * 8);
      *(uint4*)(&SM[0][r][lc * 8]) = va;
      int gn = n0 + r; if (gn > N - 1) gn = N - 1;
      uint4 vb = *(const uint4*)(B + (long long)gn * ldb + k0 + lc * 8);
      *(uint4*)(&SM[1][r][lc * 8]) = vb;
    }
    __syncthreads();
    short8 af[4], bfr[4];
    #pragma unroll
    for (int i = 0; i < 4; i++) af[i]  = *(const short8*)(&SM[0][wm * 64 + i * 16 + l16][quad * 8]);
    #pragma unroll
    for (int j = 0; j < 4; j++) bfr[j] = *(const short8*)(&SM[1][wn * 64 + j * 16 + l16][quad * 8]);
    #pragma unroll
    for (int i = 0; i < 4; i++)
      #pragma unroll
      for (int j = 0; j < 4; j++)
        acc[i][j] = __builtin_amdgcn_mfma_f32_16x16x32_bf16(af[i], bfr[j], acc[i][j], 0, 0, 0);
    __syncthreads();
  }

  // -------- epilogue via LDS (per-wave 16x64 fp32 slab, row stride 68) -----
  // After the loop's final __syncthreads all waves are done with SM tiles.
  float* cs = (float*)(&SM[0][0][0]) + wid * (16 * 68);   // 4352 B per wave
  int erow = lane >> 2;        // 0..15  (within 16-row slab)
  int eq   = lane & 3;

  #pragma unroll
  for (int i = 0; i < 4; i++) {
    // dump acc[i][*] : C/D layout row = quad*4+reg, col = j*16 + l16
    #pragma unroll
    for (int j = 0; j < 4; j++)
      #pragma unroll
      for (int r = 0; r < 4; r++)
        cs[(quad * 4 + r) * 68 + j * 16 + l16] = acc[i][j][r];
    // same-wave LDS ops are in-order; compiler inserts lgkmcnt waits
    int grow = m0 + wm * 64 + i * 16 + erow;
    bool rowok = grow < M;

    if constexpr (EPI == EPI_BIAS_RES_F32) {
      #pragma unroll
      for (int t = 0; t < 4; t++) {
        int colb = t * 16 + eq * 4;                  // lanes 0..3 cover 64B
        int gcol = n0 + wn * 64 + colb;
        if (!rowok || gcol >= N) continue;
        float4 vv = *(const float4*)&cs[erow * 68 + colb];
        float4 bb = *(const float4*)&bias[gcol];
        const float4 rr = *(const float4*)&res[(long long)grow * ldc + gcol];
        vv.x += bb.x + rr.x; vv.y += bb.y + rr.y;
        vv.z += bb.z + rr.z; vv.w += bb.w + rr.w;
        *(float4*)((float*)Cout + cOff + (long long)grow * ldc + gcol) = vv;
      }
    } else {
      #pragma unroll
      for (int h = 0; h < 2; h++) {
        int colb = h * 32 + eq * 8;                  // lanes 0..3 cover 64B
        int gcol = n0 + wn * 64 + colb;
        if (!rowok || gcol >= N) continue;           // N % 8 == 0 in all uses
        float4 a0 = *(const float4*)&cs[erow * 68 + colb];
        float4 a1 = *(const float4*)&cs[erow * 68 + colb + 4];
        float vs[8] = {a0.x, a0.y, a0.z, a0.w, a1.x, a1.y, a1.z, a1.w};
        if constexpr (EPI == EPI_BIAS_GELU_BF16) {
          float4 b0 = *(const float4*)&bias[gcol];
          float4 b1 = *(const float4*)&bias[gcol + 4];
          float bs[8] = {b0.x, b0.y, b0.z, b0.w, b1.x, b1.y, b1.z, b1.w};
          #pragma unroll
          for (int e = 0; e < 8; e++) {
            float tt = vs[e] + bs[e];
            // fast_gelu = t * sigmoid(1.702 t);  exp(-1.702t) = 2^(-2.45547t)
            float ex = __builtin_amdgcn_exp2f(tt * -2.4554669595930156f);
            vs[e] = tt / (1.f + ex);
          }
        } else if constexpr (EPI == EPI_SCALE_BF16) {
          #pragma unroll
          for (int e = 0; e < 8; e++) vs[e] *= scale;
        }
        union { unsigned short s[8]; uint4 u; } p;
        #pragma unroll
        for (int e = 0; e < 8; e++) p.s[e] = f2bf(vs[e]);
        *(uint4*)((unsigned short*)Cout + cOff + (long long)grow * ldc + gcol) = p.u;
      }
    }
    // next i overwrites cs; same-wave LDS WAR is in-order
  }
}

// ----------------------------------------------------------------------------
extern "C" void kernel_launch(void* const* d_in, const int* in_sizes, int n_in,
                              void* d_out, int out_size, void* d_ws, size_t ws_size,
                              hipStream_t stream) {
  const float* x   = (const float*)d_in[0];
  const float* g1  = (const float*)d_in[1];
  const float* be1 = (const float*)d_in[2];
  const float* Wq  = (const float*)d_in[3];
  const float* Wk  = (const float*)d_in[4];
  const float* Wv  = (const float*)d_in[5];
  const float* Wp  = (const float*)d_in[6];
  const float* bp  = (const float*)d_in[7];
  const float* g2  = (const float*)d_in[8];
  const float* be2 = (const float*)d_in[9];
  const float* W1  = (const float*)d_in[10];
  const float* b1  = (const float*)d_in[11];
  const float* W2  = (const float*)d_in[12];
  const float* b2  = (const float*)d_in[13];
  float* out = (float*)d_out;

  char* ws = (char*)d_ws;
  size_t off = 0;
  auto alloc = [&](size_t bytes) {
    size_t r = off; off += (bytes + 255) & ~(size_t)255; return r;
  };
  unsigned short* wq_bf = (unsigned short*)(ws + alloc((size_t)DIM * DIM * 2));
  unsigned short* wk_bf = (unsigned short*)(ws + alloc((size_t)DIM * DIM * 2));
  unsigned short* wv_bf = (unsigned short*)(ws + alloc((size_t)DIM * DIM * 2));
  unsigned short* wp_bf = (unsigned short*)(ws + alloc((size_t)DIM * DIM * 2));
  unsigned short* w1_bf = (unsigned short*)(ws + alloc((size_t)HIDDEN * DIM * 2));
  unsigned short* w2_bf = (unsigned short*)(ws + alloc((size_t)HIDDEN * DIM * 2));
  unsigned short* h_bf  = (unsigned short*)(ws + alloc((size_t)M_ROWS * DIM * 2));  // ln1 out; later o; later ln2 out
  unsigned short* q_bf  = (unsigned short*)(ws + alloc((size_t)M_ROWS * DIM * 2));
  unsigned short* k_bf  = (unsigned short*)(ws + alloc((size_t)M_ROWS * DIM * 2));
  unsigned short* v_bf  = (unsigned short*)(ws + alloc((size_t)M_ROWS * DIM * 2));
  unsigned short* vt_bf = (unsigned short*)(ws + alloc((size_t)256 * HEAD_DIM * NPAD * 2));
  size_t base_end = off;

  int G = 64;
  while (G > 16 && base_end + (((size_t)G * SEQ * NPAD * 2 + 255) & ~(size_t)255) > ws_size)
    G >>= 1;
  unsigned short* S_bf = (unsigned short*)(ws + alloc((size_t)G * SEQ * NPAD * 2));

  unsigned short* o_bf  = h_bf;   // o written after h (ln1 out) is dead
  unsigned short* h2_bf = h_bf;   // ln2 out written after o consumed
  unsigned short* u_bf  = q_bf;   // MLP hidden (75.6 MB) over dead [q|k|v|vt] span
  float*          x1    = out;    // residual-1 result lives in d_out

  // 1. weights fp32 -> bf16
  f32_to_bf16_kernel<<<(DIM * DIM / 4 + 255) / 256, 256, 0, stream>>>(Wq, wq_bf, DIM * DIM / 4);
  f32_to_bf16_kernel<<<(DIM * DIM / 4 + 255) / 256, 256, 0, stream>>>(Wk, wk_bf, DIM * DIM / 4);
  f32_to_bf16_kernel<<<(DIM * DIM / 4 + 255) / 256, 256, 0, stream>>>(Wv, wv_bf, DIM * DIM / 4);
  f32_to_bf16_kernel<<<(DIM * DIM / 4 + 255) / 256, 256, 0, stream>>>(Wp, wp_bf, DIM * DIM / 4);
  f32_to_bf16_kernel<<<(HIDDEN * DIM / 4 + 255) / 256, 256, 0, stream>>>(W1, w1_bf, HIDDEN * DIM / 4);
  f32_to_bf16_kernel<<<(HIDDEN * DIM / 4 + 255) / 256, 256, 0, stream>>>(W2, w2_bf, HIDDEN * DIM / 4);

  // 2. h = LN1(x)
  ln_kernel<<<M_ROWS, 256, 0, stream>>>(x, g1, be1, h_bf);

  // 3. q/k/v = h @ W{q,k,v}^T
  dim3 gQKV(73, 8, 1);
  gemm_nt<EPI_BF16><<<gQKV, 256, 0, stream>>>(h_bf, DIM, 0, 0, wq_bf, DIM, 0, 0,
      q_bf, DIM, 0, 0, nullptr, nullptr, M_ROWS, DIM, DIM, 1.f);
  gemm_nt<EPI_BF16><<<gQKV, 256, 0, stream>>>(h_bf, DIM, 0, 0, wk_bf, DIM, 0, 0,
      k_bf, DIM, 0, 0, nullptr, nullptr, M_ROWS, DIM, DIM, 1.f);
  gemm_nt<EPI_BF16><<<gQKV, 256, 0, stream>>>(h_bf, DIM, 0, 0, wv_bf, DIM, 0, 0,
      v_bf, DIM, 0, 0, nullptr, nullptr, M_ROWS, DIM, DIM, 1.f);

  // 4. vt[bh][d][n]
  transpose_v_kernel<<<256 * HEAD_DIM * (NPAD / 8) / 256, 256, 0, stream>>>(v_bf, vt_bf);

  // 5-7. attention, chunked over G heads
  for (int g = 0; g < 256; g += G) {
    int bb0 = g >> 4;
    // S = (Q K^T) * scale ; N passed as NPAD so pad cols are stored (finite
    // garbage from B-row clamp), softmax overwrites them with zeros.
    gemm_nt<EPI_SCALE_BF16><<<dim3(5, 5, G), 256, 0, stream>>>(
        q_bf + (size_t)bb0 * SEQ * DIM, DIM, (long long)SEQ * DIM, HEAD_DIM,
        k_bf + (size_t)bb0 * SEQ * DIM, DIM, (long long)SEQ * DIM, HEAD_DIM,
        S_bf, NPAD, 16LL * SEQ * NPAD, (long long)SEQ * NPAD,
        nullptr, nullptr, SEQ, NPAD, HEAD_DIM, 0.125f);
    softmax_kernel<<<G * SEQ / 4, 256, 0, stream>>>(S_bf);
    gemm_nt<EPI_BF16><<<dim3(5, 1, G), 256, 0, stream>>>(
        S_bf, NPAD, 16LL * SEQ * NPAD, (long long)SEQ * NPAD,
        vt_bf + (size_t)g * HEAD_DIM * NPAD, NPAD, 16LL * HEAD_DIM * NPAD, (long long)HEAD_DIM * NPAD,
        o_bf + (size_t)bb0 * SEQ * DIM, DIM, (long long)SEQ * DIM, HEAD_DIM,
        nullptr, nullptr, SEQ, HEAD_DIM, NPAD, 1.f);
  }

  // 8. x1 = x + O @ Wp^T + bp   (x1 lives in d_out)
  gemm_nt<EPI_BIAS_RES_F32><<<gQKV, 256, 0, stream>>>(o_bf, DIM, 0, 0, wp_bf, DIM, 0, 0,
      x1, DIM, 0, 0, bp, x, M_ROWS, DIM, DIM, 1.f);

  // 9. h2 = LN2(x1)
  ln_kernel<<<M_ROWS, 256, 0, stream>>>(x1, g2, be2, h2_bf);

  // 10. u = fast_gelu(h2 @ W1^T + b1)
  dim3 gM1(73, 32, 1);
  gemm_nt<EPI_BIAS_GELU_BF16><<<gM1, 256, 0, stream>>>(h2_bf, DIM, 0, 0, w1_bf, DIM, 0, 0,
      u_bf, HIDDEN, 0, 0, b1, nullptr, M_ROWS, HIDDEN, DIM, 1.f);

  // 11. out = x1 + u @ W2^T + b2
  gemm_nt<EPI_BIAS_RES_F32><<<gQKV, 256, 0, stream>>>(u_bf, HIDDEN, 0, 0, w2_bf, HIDDEN, 0, 0,
      out, DIM, 0, 0, b2, x1, M_ROWS, DIM, HIDDEN, 1.f);
}

// Round 4
// 830.093 us; speedup vs baseline: 2.1108x; 1.0463x over previous
//
#include <hip/hip_runtime.h>

typedef short  short8  __attribute__((ext_vector_type(8)));
typedef float  float4v __attribute__((ext_vector_type(4)));

#define DIM      1024
#define HEADS    16
#define HEAD_DIM 64
#define HIDDEN   4096
#define BATCH    16
#define SEQ      577
#define M_ROWS   (BATCH*SEQ)   /* 9232 */
#define NPAD     608           /* 577 padded to 19*32 */
#define LOG2E    1.4426950408889634f

static __device__ __forceinline__ unsigned short f2bf(float f) {
  unsigned int u = __float_as_uint(f);
  u += 0x7FFFu + ((u >> 16) & 1u);           // round-to-nearest-even
  return (unsigned short)(u >> 16);
}
static __device__ __forceinline__ float bf2f(unsigned short h) {
  return __uint_as_float(((unsigned int)h) << 16);
}
// async global->LDS, 16B per lane; LDS dest = wave-uniform base + lane*16
static __device__ __forceinline__ void gload_lds16(const void* g, void* l) {
  __builtin_amdgcn_global_load_lds(
      (const __attribute__((address_space(1))) void*)g,
      (__attribute__((address_space(3))) void*)l, 16, 0, 0);
}

// ---------------------------------------------------------------- fp32 -> bf16
__global__ __launch_bounds__(256) void f32_to_bf16_kernel(
    const float* __restrict__ in, unsigned short* __restrict__ out, int n4) {
  int i = blockIdx.x * 256 + threadIdx.x;
  if (i >= n4) return;
  float4 v = ((const float4*)in)[i];
  union { unsigned short s[4]; uint2 u; } p;
  p.s[0] = f2bf(v.x); p.s[1] = f2bf(v.y); p.s[2] = f2bf(v.z); p.s[3] = f2bf(v.w);
  ((uint2*)out)[i] = p.u;
}

// ---------------------------------------------------------------- LayerNorm row
__global__ __launch_bounds__(256) void ln_kernel(
    const float* __restrict__ x, const float* __restrict__ g,
    const float* __restrict__ b, unsigned short* __restrict__ out) {
  int row = blockIdx.x, tid = threadIdx.x;
  const float* xr = x + (long long)row * DIM;
  float4 v = *(const float4*)(xr + tid * 4);
  float s1 = v.x + v.y + v.z + v.w;
  float s2 = v.x*v.x + v.y*v.y + v.z*v.z + v.w*v.w;
  #pragma unroll
  for (int o = 32; o; o >>= 1) { s1 += __shfl_xor(s1, o); s2 += __shfl_xor(s2, o); }
  __shared__ float a1[4], a2[4];
  int wid = tid >> 6, lane = tid & 63;
  if (lane == 0) { a1[wid] = s1; a2[wid] = s2; }
  __syncthreads();
  s1 = a1[0] + a1[1] + a1[2] + a1[3];
  s2 = a2[0] + a2[1] + a2[2] + a2[3];
  float mean = s1 * (1.f / DIM);
  float var  = s2 * (1.f / DIM) - mean * mean;
  float rstd = rsqrtf(var + 1e-5f);
  float4 gv = *(const float4*)(g + tid * 4);
  float4 bv = *(const float4*)(b + tid * 4);
  union { unsigned short s[4]; uint2 u; } p;
  p.s[0] = f2bf((v.x - mean) * rstd * gv.x + bv.x);
  p.s[1] = f2bf((v.y - mean) * rstd * gv.y + bv.y);
  p.s[2] = f2bf((v.z - mean) * rstd * gv.z + bv.z);
  p.s[3] = f2bf((v.w - mean) * rstd * gv.w + bv.w);
  *(uint2*)(out + (long long)row * DIM + tid * 4) = p.u;
}

// ---------------------------------------------------------------- V transpose
__global__ __launch_bounds__(256) void transpose_v_kernel(
    const unsigned short* __restrict__ v, unsigned short* __restrict__ vt) {
  int t = blockIdx.x * 256 + threadIdx.x;          // exactly 256*64*76 threads
  int chunk = t % 76;
  int rest  = t / 76;
  int d  = rest & 63;
  int bh = rest >> 6;
  int b = bh >> 4, h = bh & 15;
  union { unsigned short s[8]; uint4 u; } p;
  #pragma unroll
  for (int i = 0; i < 8; i++) {
    int n = chunk * 8 + i;
    p.s[i] = (n < SEQ) ? v[((long long)(b * SEQ + n)) * DIM + h * HEAD_DIM + d] : (unsigned short)0;
  }
  *(uint4*)(vt + ((long long)bh * HEAD_DIM + d) * NPAD + chunk * 8) = p.u;
}

// ---------------------------------------------------------------- row softmax
__global__ __launch_bounds__(256) void softmax_kernel(unsigned short* __restrict__ S) {
  int lane = threadIdx.x & 63;
  int row  = blockIdx.x * 4 + (threadIdx.x >> 6);
  unsigned short* r = S + (long long)row * NPAD;
  float s[10];
  float m = -1e30f;
  #pragma unroll
  for (int j = 0; j < 10; j++) {
    int col = j * 64 + lane;
    s[j] = (col < SEQ) ? bf2f(r[col]) : -1e30f;
    m = fmaxf(m, s[j]);
  }
  #pragma unroll
  for (int o = 32; o; o >>= 1) m = fmaxf(m, __shfl_xor(m, o));
  float sum = 0.f;
  #pragma unroll
  for (int j = 0; j < 10; j++) {
    int col = j * 64 + lane;
    float e = (col < SEQ) ? __builtin_amdgcn_exp2f((s[j] - m) * LOG2E) : 0.f;
    s[j] = e; sum += e;
  }
  #pragma unroll
  for (int o = 32; o; o >>= 1) sum += __shfl_xor(sum, o);
  float inv = 1.f / sum;
  #pragma unroll
  for (int j = 0; j < 10; j++) {
    int col = j * 64 + lane;
    if (col < NPAD) r[col] = (col < SEQ) ? f2bf(s[j] * inv) : (unsigned short)0;
  }
}

// ---------------------------------------------------------------- NT GEMM
// C[M,N] = A[M,K] (row-major, bf16) * B[N,K]^T (row-major, bf16)
// block 128x128, 4 waves 2x2, each wave 64x64 via 4x4 mfma 16x16x32.
// K-loop staging via global_load_lds width=16 (m97 structure): unpadded
// [128][32] tiles, per-wave uniform LDS base, per-lane global addr.
// Epilogue via per-wave LDS slab (anti-spill, R3-verified).
enum { EPI_BF16 = 0, EPI_SCALE_BF16 = 1, EPI_BIAS_RES_F32 = 2, EPI_BIAS_GELU_BF16 = 3 };

template <int EPI>
__global__ __launch_bounds__(256, 2) void gemm_nt(
    const unsigned short* __restrict__ A, int lda, long long sAb, long long sAh,
    const unsigned short* __restrict__ B, int ldb, long long sBb, long long sBh,
    void* __restrict__ Cout, int ldc, long long sCb, long long sCh,
    const float* __restrict__ bias, const float* __restrict__ res,
    int M, int N, int K, float scale) {
  int bh = blockIdx.z;
  int bb = bh >> 4, hh = bh & 15;
  A += bb * sAb + hh * sAh;
  B += bb * sBb + hh * sBh;
  long long cOff = bb * sCb + hh * sCh;

  int m0 = blockIdx.x * 128, n0 = blockIdx.y * 128;
  int tid = threadIdx.x;
  int lane = tid & 63, wid = tid >> 6;
  int wm = wid >> 1, wn = wid & 1;
  int quad = lane >> 4, l16 = lane & 15;

  // K-loop: As[128][32] + Bs[128][32] = 16384 B; epilogue: 4*16*68*4 = 17408 B
  __shared__ __align__(16) char SMEM[17408];
  unsigned short* As = (unsigned short*)SMEM;        // [128][32] unpadded
  unsigned short* Bs = As + 128 * 32;

  float4v acc[4][4];
  #pragma unroll
  for (int i = 0; i < 4; i++)
    #pragma unroll
    for (int j = 0; j < 4; j++) acc[i][j] = (float4v){0.f, 0.f, 0.f, 0.f};

  int lr  = lane >> 2;   // 0..15 row within 16-row group
  int lch = lane & 3;    // 16B chunk within 64B row

  for (int k0 = 0; k0 < K; k0 += 32) {
    #pragma unroll
    for (int p = 0; p < 2; p++) {
      int ra = wid * 32 + p * 16;                    // wave-uniform tile row base
      int gr = m0 + ra + lr; if (gr > M - 1) gr = M - 1;
      gload_lds16(A + (long long)gr * lda + k0 + lch * 8, As + ra * 32);
      int gn = n0 + ra + lr; if (gn > N - 1) gn = N - 1;
      gload_lds16(B + (long long)gn * ldb + k0 + lch * 8, Bs + ra * 32);
    }
    __syncthreads();      // compiler drains vmcnt before s_barrier
    short8 af[4], bfr[4];
    #pragma unroll
    for (int i = 0; i < 4; i++) af[i]  = *(const short8*)(As + (wm * 64 + i * 16 + l16) * 32 + quad * 8);
    #pragma unroll
    for (int j = 0; j < 4; j++) bfr[j] = *(const short8*)(Bs + (wn * 64 + j * 16 + l16) * 32 + quad * 8);
    #pragma unroll
    for (int i = 0; i < 4; i++)
      #pragma unroll
      for (int j = 0; j < 4; j++)
        acc[i][j] = __builtin_amdgcn_mfma_f32_16x16x32_bf16(af[i], bfr[j], acc[i][j], 0, 0, 0);
    __syncthreads();
  }

  // -------- epilogue via LDS (per-wave 16x64 fp32 slab, row stride 68) -----
  float* cs = (float*)SMEM + wid * (16 * 68);        // 4352 B per wave
  int erow = lane >> 2;        // 0..15 (within 16-row slab)
  int eq   = lane & 3;

  #pragma unroll
  for (int i = 0; i < 4; i++) {
    // dump acc[i][*] : C/D layout row = quad*4+reg, col = j*16 + l16
    #pragma unroll
    for (int j = 0; j < 4; j++)
      #pragma unroll
      for (int r = 0; r < 4; r++)
        cs[(quad * 4 + r) * 68 + j * 16 + l16] = acc[i][j][r];
    // same-wave LDS ops are in-order; compiler inserts lgkmcnt waits
    int grow = m0 + wm * 64 + i * 16 + erow;
    bool rowok = grow < M;

    if constexpr (EPI == EPI_BIAS_RES_F32) {
      #pragma unroll
      for (int t = 0; t < 4; t++) {
        int colb = t * 16 + eq * 4;                  // lanes 0..3 cover 64B
        int gcol = n0 + wn * 64 + colb;
        if (!rowok || gcol >= N) continue;
        float4 vv = *(const float4*)&cs[erow * 68 + colb];
        float4 bb = *(const float4*)&bias[gcol];
        const float4 rr = *(const float4*)&res[(long long)grow * ldc + gcol];
        vv.x += bb.x + rr.x; vv.y += bb.y + rr.y;
        vv.z += bb.z + rr.z; vv.w += bb.w + rr.w;
        *(float4*)((float*)Cout + cOff + (long long)grow * ldc + gcol) = vv;
      }
    } else {
      #pragma unroll
      for (int h = 0; h < 2; h++) {
        int colb = h * 32 + eq * 8;                  // lanes 0..3 cover 64B
        int gcol = n0 + wn * 64 + colb;
        if (!rowok || gcol >= N) continue;           // N % 8 == 0 in all uses
        float4 a0 = *(const float4*)&cs[erow * 68 + colb];
        float4 a1 = *(const float4*)&cs[erow * 68 + colb + 4];
        float vs[8] = {a0.x, a0.y, a0.z, a0.w, a1.x, a1.y, a1.z, a1.w};
        if constexpr (EPI == EPI_BIAS_GELU_BF16) {
          float4 b0 = *(const float4*)&bias[gcol];
          float4 b1 = *(const float4*)&bias[gcol + 4];
          float bs[8] = {b0.x, b0.y, b0.z, b0.w, b1.x, b1.y, b1.z, b1.w};
          #pragma unroll
          for (int e = 0; e < 8; e++) {
            float tt = vs[e] + bs[e];
            // fast_gelu = t * sigmoid(1.702 t);  exp(-1.702t) = 2^(-2.45547t)
            float ex = __builtin_amdgcn_exp2f(tt * -2.4554669595930156f);
            vs[e] = tt / (1.f + ex);
          }
        } else if constexpr (EPI == EPI_SCALE_BF16) {
          #pragma unroll
          for (int e = 0; e < 8; e++) vs[e] *= scale;
        }
        union { unsigned short s[8]; uint4 u; } p;
        #pragma unroll
        for (int e = 0; e < 8; e++) p.s[e] = f2bf(vs[e]);
        *(uint4*)((unsigned short*)Cout + cOff + (long long)grow * ldc + gcol) = p.u;
      }
    }
    // next i overwrites cs; same-wave LDS WAR is in-order
  }
}

// ----------------------------------------------------------------------------
extern "C" void kernel_launch(void* const* d_in, const int* in_sizes, int n_in,
                              void* d_out, int out_size, void* d_ws, size_t ws_size,
                              hipStream_t stream) {
  const float* x   = (const float*)d_in[0];
  const float* g1  = (const float*)d_in[1];
  const float* be1 = (const float*)d_in[2];
  const float* Wq  = (const float*)d_in[3];
  const float* Wk  = (const float*)d_in[4];
  const float* Wv  = (const float*)d_in[5];
  const float* Wp  = (const float*)d_in[6];
  const float* bp  = (const float*)d_in[7];
  const float* g2  = (const float*)d_in[8];
  const float* be2 = (const float*)d_in[9];
  const float* W1  = (const float*)d_in[10];
  const float* b1  = (const float*)d_in[11];
  const float* W2  = (const float*)d_in[12];
  const float* b2  = (const float*)d_in[13];
  float* out = (float*)d_out;

  char* ws = (char*)d_ws;
  size_t off = 0;
  auto alloc = [&](size_t bytes) {
    size_t r = off; off += (bytes + 255) & ~(size_t)255; return r;
  };
  unsigned short* wq_bf = (unsigned short*)(ws + alloc((size_t)DIM * DIM * 2));
  unsigned short* wk_bf = (unsigned short*)(ws + alloc((size_t)DIM * DIM * 2));
  unsigned short* wv_bf = (unsigned short*)(ws + alloc((size_t)DIM * DIM * 2));
  unsigned short* wp_bf = (unsigned short*)(ws + alloc((size_t)DIM * DIM * 2));
  unsigned short* w1_bf = (unsigned short*)(ws + alloc((size_t)HIDDEN * DIM * 2));
  unsigned short* w2_bf = (unsigned short*)(ws + alloc((size_t)HIDDEN * DIM * 2));
  unsigned short* h_bf  = (unsigned short*)(ws + alloc((size_t)M_ROWS * DIM * 2));  // ln1 out; later o; later ln2 out
  unsigned short* q_bf  = (unsigned short*)(ws + alloc((size_t)M_ROWS * DIM * 2));
  unsigned short* k_bf  = (unsigned short*)(ws + alloc((size_t)M_ROWS * DIM * 2));
  unsigned short* v_bf  = (unsigned short*)(ws + alloc((size_t)M_ROWS * DIM * 2));
  unsigned short* vt_bf = (unsigned short*)(ws + alloc((size_t)256 * HEAD_DIM * NPAD * 2));
  size_t base_end = off;

  int G = 64;
  while (G > 16 && base_end + (((size_t)G * SEQ * NPAD * 2 + 255) & ~(size_t)255) > ws_size)
    G >>= 1;
  unsigned short* S_bf = (unsigned short*)(ws + alloc((size_t)G * SEQ * NPAD * 2));

  unsigned short* o_bf  = h_bf;   // o written after h (ln1 out) is dead
  unsigned short* h2_bf = h_bf;   // ln2 out written after o consumed
  unsigned short* u_bf  = q_bf;   // MLP hidden (75.6 MB) over dead [q|k|v|vt] span
  float*          x1    = out;    // residual-1 result lives in d_out

  // 1. weights fp32 -> bf16
  f32_to_bf16_kernel<<<(DIM * DIM / 4 + 255) / 256, 256, 0, stream>>>(Wq, wq_bf, DIM * DIM / 4);
  f32_to_bf16_kernel<<<(DIM * DIM / 4 + 255) / 256, 256, 0, stream>>>(Wk, wk_bf, DIM * DIM / 4);
  f32_to_bf16_kernel<<<(DIM * DIM / 4 + 255) / 256, 256, 0, stream>>>(Wv, wv_bf, DIM * DIM / 4);
  f32_to_bf16_kernel<<<(DIM * DIM / 4 + 255) / 256, 256, 0, stream>>>(Wp, wp_bf, DIM * DIM / 4);
  f32_to_bf16_kernel<<<(HIDDEN * DIM / 4 + 255) / 256, 256, 0, stream>>>(W1, w1_bf, HIDDEN * DIM / 4);
  f32_to_bf16_kernel<<<(HIDDEN * DIM / 4 + 255) / 256, 256, 0, stream>>>(W2, w2_bf, HIDDEN * DIM / 4);

  // 2. h = LN1(x)
  ln_kernel<<<M_ROWS, 256, 0, stream>>>(x, g1, be1, h_bf);

  // 3. q/k/v = h @ W{q,k,v}^T
  dim3 gQKV(73, 8, 1);
  gemm_nt<EPI_BF16><<<gQKV, 256, 0, stream>>>(h_bf, DIM, 0, 0, wq_bf, DIM, 0, 0,
      q_bf, DIM, 0, 0, nullptr, nullptr, M_ROWS, DIM, DIM, 1.f);
  gemm_nt<EPI_BF16><<<gQKV, 256, 0, stream>>>(h_bf, DIM, 0, 0, wk_bf, DIM, 0, 0,
      k_bf, DIM, 0, 0, nullptr, nullptr, M_ROWS, DIM, DIM, 1.f);
  gemm_nt<EPI_BF16><<<gQKV, 256, 0, stream>>>(h_bf, DIM, 0, 0, wv_bf, DIM, 0, 0,
      v_bf, DIM, 0, 0, nullptr, nullptr, M_ROWS, DIM, DIM, 1.f);

  // 4. vt[bh][d][n]
  transpose_v_kernel<<<256 * HEAD_DIM * (NPAD / 8) / 256, 256, 0, stream>>>(v_bf, vt_bf);

  // 5-7. attention, chunked over G heads
  for (int g = 0; g < 256; g += G) {
    int bb0 = g >> 4;
    gemm_nt<EPI_SCALE_BF16><<<dim3(5, 5, G), 256, 0, stream>>>(
        q_bf + (size_t)bb0 * SEQ * DIM, DIM, (long long)SEQ * DIM, HEAD_DIM,
        k_bf + (size_t)bb0 * SEQ * DIM, DIM, (long long)SEQ * DIM, HEAD_DIM,
        S_bf, NPAD, 16LL * SEQ * NPAD, (long long)SEQ * NPAD,
        nullptr, nullptr, SEQ, NPAD, HEAD_DIM, 0.125f);
    softmax_kernel<<<G * SEQ / 4, 256, 0, stream>>>(S_bf);
    gemm_nt<EPI_BF16><<<dim3(5, 1, G), 256, 0, stream>>>(
        S_bf, NPAD, 16LL * SEQ * NPAD, (long long)SEQ * NPAD,
        vt_bf + (size_t)g * HEAD_DIM * NPAD, NPAD, 16LL * HEAD_DIM * NPAD, (long long)HEAD_DIM * NPAD,
        o_bf + (size_t)bb0 * SEQ * DIM, DIM, (long long)SEQ * DIM, HEAD_DIM,
        nullptr, nullptr, SEQ, HEAD_DIM, NPAD, 1.f);
  }

  // 8. x1 = x + O @ Wp^T + bp   (x1 lives in d_out)
  gemm_nt<EPI_BIAS_RES_F32><<<gQKV, 256, 0, stream>>>(o_bf, DIM, 0, 0, wp_bf, DIM, 0, 0,
      x1, DIM, 0, 0, bp, x, M_ROWS, DIM, DIM, 1.f);

  // 9. h2 = LN2(x1)
  ln_kernel<<<M_ROWS, 256, 0, stream>>>(x1, g2, be2, h2_bf);

  // 10. u = fast_gelu(h2 @ W1^T + b1)
  dim3 gM1(73, 32, 1);
  gemm_nt<EPI_BIAS_GELU_BF16><<<gM1, 256, 0, stream>>>(h2_bf, DIM, 0, 0, w1_bf, DIM, 0, 0,
      u_bf, HIDDEN, 0, 0, b1, nullptr, M_ROWS, HIDDEN, DIM, 1.f);

  // 11. out = x1 + u @ W2^T + b2
  gemm_nt<EPI_BIAS_RES_F32><<<gQKV, 256, 0, stream>>>(u_bf, HIDDEN, 0, 0, w2_bf, HIDDEN, 0, 0,
      out, DIM, 0, 0, b2, x1, M_ROWS, DIM, HIDDEN, 1.f);
}

// Round 5
// 690.558 us; speedup vs baseline: 2.5373x; 1.2021x over previous
//
#include <hip/hip_runtime.h>

typedef short  short8  __attribute__((ext_vector_type(8)));
typedef float  float4v __attribute__((ext_vector_type(4)));

#define DIM      1024
#define HEADS    16
#define HEAD_DIM 64
#define HIDDEN   4096
#define BATCH    16
#define SEQ      577
#define M_ROWS   (BATCH*SEQ)   /* 9232 */
#define NPAD2    640           /* keys padded to 10*64 */
#define QKVLD    3072          /* merged qkv row stride */
#define LOG2E    1.4426950408889634f

static __device__ __forceinline__ unsigned short f2bf(float f) {
  unsigned int u = __float_as_uint(f);
  u += 0x7FFFu + ((u >> 16) & 1u);           // round-to-nearest-even
  return (unsigned short)(u >> 16);
}
static __device__ __forceinline__ float bf2f(unsigned short h) {
  return __uint_as_float(((unsigned int)h) << 16);
}
// async global->LDS, 16B per lane; LDS dest = wave-uniform base + lane*16
static __device__ __forceinline__ void gload_lds16(const void* g, void* l) {
  __builtin_amdgcn_global_load_lds(
      (const __attribute__((address_space(1))) void*)g,
      (__attribute__((address_space(3))) void*)l, 16, 0, 0);
}

// ---------------------------------------------------------------- fp32 -> bf16
__global__ __launch_bounds__(256) void f32_to_bf16_kernel(
    const float* __restrict__ in, unsigned short* __restrict__ out, int n4) {
  int i = blockIdx.x * 256 + threadIdx.x;
  if (i >= n4) return;
  float4 v = ((const float4*)in)[i];
  union { unsigned short s[4]; uint2 u; } p;
  p.s[0] = f2bf(v.x); p.s[1] = f2bf(v.y); p.s[2] = f2bf(v.z); p.s[3] = f2bf(v.w);
  ((uint2*)out)[i] = p.u;
}

// ---------------------------------------------------------------- LayerNorm row
__global__ __launch_bounds__(256) void ln_kernel(
    const float* __restrict__ x, const float* __restrict__ g,
    const float* __restrict__ b, unsigned short* __restrict__ out) {
  int row = blockIdx.x, tid = threadIdx.x;
  const float* xr = x + (long long)row * DIM;
  float4 v = *(const float4*)(xr + tid * 4);
  float s1 = v.x + v.y + v.z + v.w;
  float s2 = v.x*v.x + v.y*v.y + v.z*v.z + v.w*v.w;
  #pragma unroll
  for (int o = 32; o; o >>= 1) { s1 += __shfl_xor(s1, o); s2 += __shfl_xor(s2, o); }
  __shared__ float a1[4], a2[4];
  int wid = tid >> 6, lane = tid & 63;
  if (lane == 0) { a1[wid] = s1; a2[wid] = s2; }
  __syncthreads();
  s1 = a1[0] + a1[1] + a1[2] + a1[3];
  s2 = a2[0] + a2[1] + a2[2] + a2[3];
  float mean = s1 * (1.f / DIM);
  float var  = s2 * (1.f / DIM) - mean * mean;
  float rstd = rsqrtf(var + 1e-5f);
  float4 gv = *(const float4*)(g + tid * 4);
  float4 bv = *(const float4*)(b + tid * 4);
  union { unsigned short s[4]; uint2 u; } p;
  p.s[0] = f2bf((v.x - mean) * rstd * gv.x + bv.x);
  p.s[1] = f2bf((v.y - mean) * rstd * gv.y + bv.y);
  p.s[2] = f2bf((v.z - mean) * rstd * gv.z + bv.z);
  p.s[3] = f2bf((v.w - mean) * rstd * gv.w + bv.w);
  *(uint2*)(out + (long long)row * DIM + tid * 4) = p.u;
}

// ---------------------------------------------------------------- V transpose
// vt[bh][d][n] (ld NPAD2, zero-padded n>=577) <- v[(b*577+n)*QKVLD + h*64 + d]
__global__ __launch_bounds__(256) void transpose_v_kernel(
    const unsigned short* __restrict__ v, unsigned short* __restrict__ vt) {
  int t = blockIdx.x * 256 + threadIdx.x;          // exactly 256*64*80 threads
  int chunk = t % 80;
  int rest  = t / 80;
  int d  = rest & 63;
  int bh = rest >> 6;
  int b = bh >> 4, h = bh & 15;
  union { unsigned short s[8]; uint4 u; } p;
  #pragma unroll
  for (int i = 0; i < 8; i++) {
    int n = chunk * 8 + i;
    p.s[i] = (n < SEQ) ? v[((long long)(b * SEQ + n)) * QKVLD + h * HEAD_DIM + d] : (unsigned short)0;
  }
  *(uint4*)(vt + ((long long)bh * HEAD_DIM + d) * NPAD2 + chunk * 8) = p.u;
}

// ---------------------------------------------------------------- flash attention
// grid (5, 256): blockIdx.x = q-tile (128 rows), blockIdx.y = bh.
// 4 waves; wave w owns q-rows w*32..w*32+31. 10 k-tiles of 64 keys.
// LDS tiles XOR-chunk-swizzled: slot c of row r holds logical 16B chunk c^(r&7)
// -> conflict-free ds_read_b128 across l16. P round-trips through LDS
// (C-layout write -> A-layout read); each wave reads only its own P rows, so
// no barrier between P-write and PV (same-wave LDS in-order).
__global__ __launch_bounds__(256, 2) void flash_attn_kernel(
    const unsigned short* __restrict__ q,   // qkv base + 0,   ld QKVLD
    const unsigned short* __restrict__ k,   // qkv base + 1024, ld QKVLD
    const unsigned short* __restrict__ vt,  // [bh][64][NPAD2]
    unsigned short* __restrict__ o) {       // [B*577][DIM]
  int qt = blockIdx.x;
  int bh = blockIdx.y;
  int b = bh >> 4, h = bh & 15;
  int q0 = qt * 128;
  int tid = threadIdx.x, lane = tid & 63, wid = tid >> 6;
  int quad = lane >> 4, l16 = lane & 15;
  long long rowbase = (long long)b * SEQ;

  __shared__ __align__(16) unsigned short SM[24576];   // 48 KB
  unsigned short* Qs = SM;            // [128][64]
  unsigned short* Ks = Qs + 128 * 64; // [64][64]
  unsigned short* Vs = Ks + 64 * 64;  // [64][64]  rows = d
  unsigned short* Ps = Vs + 64 * 64;  // [128][64]

  // stage Q once (rows clamped; garbage rows masked at store)
  #pragma unroll
  for (int p = 0; p < 4; p++) {
    int r = wid * 32 + p * 8 + (lane >> 3);
    int c = lane & 7;
    int gr = q0 + r; if (gr > SEQ - 1) gr = SEQ - 1;
    gload_lds16(q + (rowbase + gr) * QKVLD + h * HEAD_DIM + ((c ^ (r & 7)) * 8),
                Qs + (wid * 32 + p * 8) * 64);
  }

  float mst[2][4], lst[2][4];
  float4v oacc[2][4];
  #pragma unroll
  for (int i = 0; i < 2; i++)
    #pragma unroll
    for (int r = 0; r < 4; r++) { mst[i][r] = -1e30f; lst[i][r] = 0.f; }
  #pragma unroll
  for (int i = 0; i < 2; i++)
    #pragma unroll
    for (int j = 0; j < 4; j++) oacc[i][j] = (float4v){0.f, 0.f, 0.f, 0.f};

  const float CE = 0.125f * LOG2E;   // head_dim^-0.5 folded into exp2

  for (int kt = 0; kt < 10; kt++) {
    if (kt) __syncthreads();         // prior PV reads of Ks/Vs done
    #pragma unroll
    for (int p = 0; p < 2; p++) {
      int r = wid * 16 + p * 8 + (lane >> 3);
      int c = lane & 7;
      int gk = kt * 64 + r; if (gk > SEQ - 1) gk = SEQ - 1;
      gload_lds16(k + (rowbase + gk) * QKVLD + h * HEAD_DIM + ((c ^ (r & 7)) * 8),
                  Ks + (wid * 16 + p * 8) * 64);
      gload_lds16(vt + ((long long)bh * HEAD_DIM + r) * NPAD2 + kt * 64 + ((c ^ (r & 7)) * 8),
                  Vs + (wid * 16 + p * 8) * 64);
    }
    __syncthreads();                 // staging (and Q on kt=0) complete

    // ---- S = Q K^T : per wave 32 rows x 64 keys, fp32 acc
    float4v sacc[2][4];
    #pragma unroll
    for (int i = 0; i < 2; i++)
      #pragma unroll
      for (int j = 0; j < 4; j++) sacc[i][j] = (float4v){0.f, 0.f, 0.f, 0.f};
    short8 af[2][2], bfr[4][2];
    #pragma unroll
    for (int i = 0; i < 2; i++) {
      int r = wid * 32 + i * 16 + l16;
      #pragma unroll
      for (int ks = 0; ks < 2; ks++)
        af[i][ks] = *(const short8*)(Qs + r * 64 + ((ks * 4 + quad) ^ (l16 & 7)) * 8);
    }
    #pragma unroll
    for (int j = 0; j < 4; j++) {
      int r = j * 16 + l16;
      #pragma unroll
      for (int ks = 0; ks < 2; ks++)
        bfr[j][ks] = *(const short8*)(Ks + r * 64 + ((ks * 4 + quad) ^ (l16 & 7)) * 8);
    }
    #pragma unroll
    for (int i = 0; i < 2; i++)
      #pragma unroll
      for (int j = 0; j < 4; j++)
        #pragma unroll
        for (int ks = 0; ks < 2; ks++)
          sacc[i][j] = __builtin_amdgcn_mfma_f32_16x16x32_bf16(af[i][ks], bfr[j][ks], sacc[i][j], 0, 0, 0);

    // ---- online softmax (rows: quad*4+reg within 16-tile; cols: j*16+l16)
    #pragma unroll
    for (int i = 0; i < 2; i++) {
      #pragma unroll
      for (int reg = 0; reg < 4; reg++) {
        float mx = -1e30f;
        #pragma unroll
        for (int j = 0; j < 4; j++) {
          int col = kt * 64 + j * 16 + l16;
          float s = (col < SEQ) ? sacc[i][j][reg] : -1e30f;
          mx = fmaxf(mx, s);
        }
        mx = fmaxf(mx, __shfl_xor(mx, 1));
        mx = fmaxf(mx, __shfl_xor(mx, 2));
        mx = fmaxf(mx, __shfl_xor(mx, 4));
        mx = fmaxf(mx, __shfl_xor(mx, 8));
        float mnew  = fmaxf(mst[i][reg], mx);
        float alpha = __builtin_amdgcn_exp2f((mst[i][reg] - mnew) * CE);
        mst[i][reg] = mnew;
        int prow = wid * 32 + i * 16 + quad * 4 + reg;
        float rs = 0.f;
        #pragma unroll
        for (int j = 0; j < 4; j++) {
          int col = kt * 64 + j * 16 + l16;
          float pv = (col < SEQ) ? __builtin_amdgcn_exp2f((sacc[i][j][reg] - mnew) * CE) : 0.f;
          rs += pv;
          int pcol = j * 16 + l16;
          Ps[prow * 64 + (((pcol >> 3) ^ (prow & 7)) * 8) + (pcol & 7)] = f2bf(pv);
        }
        rs += __shfl_xor(rs, 1); rs += __shfl_xor(rs, 2);
        rs += __shfl_xor(rs, 4); rs += __shfl_xor(rs, 8);
        lst[i][reg] = lst[i][reg] * alpha + rs;
        #pragma unroll
        for (int j = 0; j < 4; j++) oacc[i][j][reg] *= alpha;
      }
    }

    // ---- O += P V : reads own P rows (same-wave, in-order) + Vs
    short8 paf[2][2], vbf[4][2];
    #pragma unroll
    for (int i = 0; i < 2; i++) {
      int r = wid * 32 + i * 16 + l16;
      #pragma unroll
      for (int kk = 0; kk < 2; kk++)
        paf[i][kk] = *(const short8*)(Ps + r * 64 + ((kk * 4 + quad) ^ (l16 & 7)) * 8);
    }
    #pragma unroll
    for (int j = 0; j < 4; j++) {
      int r = j * 16 + l16;                          // d index
      #pragma unroll
      for (int kk = 0; kk < 2; kk++)
        vbf[j][kk] = *(const short8*)(Vs + r * 64 + ((kk * 4 + quad) ^ (l16 & 7)) * 8);
    }
    #pragma unroll
    for (int i = 0; i < 2; i++)
      #pragma unroll
      for (int j = 0; j < 4; j++)
        #pragma unroll
        for (int kk = 0; kk < 2; kk++)
          oacc[i][j] = __builtin_amdgcn_mfma_f32_16x16x32_bf16(paf[i][kk], vbf[j][kk], oacc[i][j], 0, 0, 0);
  }

  // ---- normalize + store (row guard covers clamped/garbage q-rows)
  #pragma unroll
  for (int i = 0; i < 2; i++) {
    #pragma unroll
    for (int reg = 0; reg < 4; reg++) {
      int grow = q0 + wid * 32 + i * 16 + quad * 4 + reg;
      if (grow >= SEQ) continue;
      float inv = 1.f / lst[i][reg];
      #pragma unroll
      for (int j = 0; j < 4; j++) {
        int d = j * 16 + l16;
        o[(rowbase + grow) * DIM + h * HEAD_DIM + d] = f2bf(oacc[i][j][reg] * inv);
      }
    }
  }
}

// ---------------------------------------------------------------- NT GEMM
// C[M,N] = A[M,K] (row-major, bf16) * B[N,K]^T (row-major, bf16)
// block 128x128, 4 waves 2x2, each wave 64x64 via 4x4 mfma 16x16x32.
// global_load_lds width=16 staging; LDS-slab epilogue (anti-spill, R3).
enum { EPI_BF16 = 0, EPI_BIAS_RES_F32 = 2, EPI_BIAS_GELU_BF16 = 3 };

template <int EPI>
__global__ __launch_bounds__(256, 2) void gemm_nt(
    const unsigned short* __restrict__ A, int lda,
    const unsigned short* __restrict__ B, int ldb,
    void* __restrict__ Cout, int ldc,
    const float* __restrict__ bias, const float* __restrict__ res,
    int M, int N, int K) {
  int m0 = blockIdx.x * 128, n0 = blockIdx.y * 128;
  int tid = threadIdx.x;
  int lane = tid & 63, wid = tid >> 6;
  int wm = wid >> 1, wn = wid & 1;
  int quad = lane >> 4, l16 = lane & 15;

  // K-loop: As[128][32] + Bs[128][32] = 16384 B; epilogue: 4*16*68*4 = 17408 B
  __shared__ __align__(16) char SMEM[17408];
  unsigned short* As = (unsigned short*)SMEM;        // [128][32] unpadded
  unsigned short* Bs = As + 128 * 32;

  float4v acc[4][4];
  #pragma unroll
  for (int i = 0; i < 4; i++)
    #pragma unroll
    for (int j = 0; j < 4; j++) acc[i][j] = (float4v){0.f, 0.f, 0.f, 0.f};

  int lr  = lane >> 2;   // 0..15 row within 16-row group
  int lch = lane & 3;    // 16B chunk within 64B row

  for (int k0 = 0; k0 < K; k0 += 32) {
    #pragma unroll
    for (int p = 0; p < 2; p++) {
      int ra = wid * 32 + p * 16;                    // wave-uniform tile row base
      int gr = m0 + ra + lr; if (gr > M - 1) gr = M - 1;
      gload_lds16(A + (long long)gr * lda + k0 + lch * 8, As + ra * 32);
      int gn = n0 + ra + lr; if (gn > N - 1) gn = N - 1;
      gload_lds16(B + (long long)gn * ldb + k0 + lch * 8, Bs + ra * 32);
    }
    __syncthreads();
    short8 af[4], bfr[4];
    #pragma unroll
    for (int i = 0; i < 4; i++) af[i]  = *(const short8*)(As + (wm * 64 + i * 16 + l16) * 32 + quad * 8);
    #pragma unroll
    for (int j = 0; j < 4; j++) bfr[j] = *(const short8*)(Bs + (wn * 64 + j * 16 + l16) * 32 + quad * 8);
    #pragma unroll
    for (int i = 0; i < 4; i++)
      #pragma unroll
      for (int j = 0; j < 4; j++)
        acc[i][j] = __builtin_amdgcn_mfma_f32_16x16x32_bf16(af[i], bfr[j], acc[i][j], 0, 0, 0);
    __syncthreads();
  }

  // -------- epilogue via LDS (per-wave 16x64 fp32 slab, row stride 68) -----
  float* cs = (float*)SMEM + wid * (16 * 68);
  int erow = lane >> 2;
  int eq   = lane & 3;

  #pragma unroll
  for (int i = 0; i < 4; i++) {
    #pragma unroll
    for (int j = 0; j < 4; j++)
      #pragma unroll
      for (int r = 0; r < 4; r++)
        cs[(quad * 4 + r) * 68 + j * 16 + l16] = acc[i][j][r];
    int grow = m0 + wm * 64 + i * 16 + erow;
    bool rowok = grow < M;

    if constexpr (EPI == EPI_BIAS_RES_F32) {
      #pragma unroll
      for (int t = 0; t < 4; t++) {
        int colb = t * 16 + eq * 4;
        int gcol = n0 + wn * 64 + colb;
        if (!rowok || gcol >= N) continue;
        float4 vv = *(const float4*)&cs[erow * 68 + colb];
        float4 bb = *(const float4*)&bias[gcol];
        const float4 rr = *(const float4*)&res[(long long)grow * ldc + gcol];
        vv.x += bb.x + rr.x; vv.y += bb.y + rr.y;
        vv.z += bb.z + rr.z; vv.w += bb.w + rr.w;
        *(float4*)((float*)Cout + (long long)grow * ldc + gcol) = vv;
      }
    } else {
      #pragma unroll
      for (int h = 0; h < 2; h++) {
        int colb = h * 32 + eq * 8;
        int gcol = n0 + wn * 64 + colb;
        if (!rowok || gcol >= N) continue;
        float4 a0 = *(const float4*)&cs[erow * 68 + colb];
        float4 a1 = *(const float4*)&cs[erow * 68 + colb + 4];
        float vs[8] = {a0.x, a0.y, a0.z, a0.w, a1.x, a1.y, a1.z, a1.w};
        if constexpr (EPI == EPI_BIAS_GELU_BF16) {
          float4 b0 = *(const float4*)&bias[gcol];
          float4 b1 = *(const float4*)&bias[gcol + 4];
          float bs[8] = {b0.x, b0.y, b0.z, b0.w, b1.x, b1.y, b1.z, b1.w};
          #pragma unroll
          for (int e = 0; e < 8; e++) {
            float tt = vs[e] + bs[e];
            float ex = __builtin_amdgcn_exp2f(tt * -2.4554669595930156f);
            vs[e] = tt / (1.f + ex);
          }
        }
        union { unsigned short s[8]; uint4 u; } p;
        #pragma unroll
        for (int e = 0; e < 8; e++) p.s[e] = f2bf(vs[e]);
        *(uint4*)((unsigned short*)Cout + (long long)grow * ldc + gcol) = p.u;
      }
    }
  }
}

// ----------------------------------------------------------------------------
extern "C" void kernel_launch(void* const* d_in, const int* in_sizes, int n_in,
                              void* d_out, int out_size, void* d_ws, size_t ws_size,
                              hipStream_t stream) {
  const float* x   = (const float*)d_in[0];
  const float* g1  = (const float*)d_in[1];
  const float* be1 = (const float*)d_in[2];
  const float* Wq  = (const float*)d_in[3];
  const float* Wk  = (const float*)d_in[4];
  const float* Wv  = (const float*)d_in[5];
  const float* Wp  = (const float*)d_in[6];
  const float* bp  = (const float*)d_in[7];
  const float* g2  = (const float*)d_in[8];
  const float* be2 = (const float*)d_in[9];
  const float* W1  = (const float*)d_in[10];
  const float* b1  = (const float*)d_in[11];
  const float* W2  = (const float*)d_in[12];
  const float* b2  = (const float*)d_in[13];
  float* out = (float*)d_out;

  char* ws = (char*)d_ws;
  size_t off = 0;
  auto alloc = [&](size_t bytes) {
    size_t r = off; off += (bytes + 255) & ~(size_t)255; return r;
  };
  unsigned short* wqkv_bf = (unsigned short*)(ws + alloc((size_t)3 * DIM * DIM * 2)); // [Wq;Wk;Wv]
  unsigned short* wp_bf   = (unsigned short*)(ws + alloc((size_t)DIM * DIM * 2));
  unsigned short* w1_bf   = (unsigned short*)(ws + alloc((size_t)HIDDEN * DIM * 2));
  unsigned short* w2_bf   = (unsigned short*)(ws + alloc((size_t)HIDDEN * DIM * 2));
  unsigned short* h_bf    = (unsigned short*)(ws + alloc((size_t)M_ROWS * DIM * 2));  // ln1; later o; later ln2
  unsigned short* qkv_bf  = (unsigned short*)(ws + alloc((size_t)M_ROWS * QKVLD * 2));
  unsigned short* vt_bf   = (unsigned short*)(ws + alloc((size_t)256 * HEAD_DIM * NPAD2 * 2));

  unsigned short* o_bf  = h_bf;     // o written after ln1-out dead
  unsigned short* h2_bf = h_bf;     // ln2-out after o consumed
  unsigned short* u_bf  = qkv_bf;   // MLP hidden (75.6 MB) over dead [qkv|vt] span (77.7 MB)
  float*          x1    = out;      // residual-1 lives in d_out

  // 1. weights fp32 -> bf16 (qkv weights into stacked [3072][1024])
  f32_to_bf16_kernel<<<DIM * DIM / 4 / 256, 256, 0, stream>>>(Wq, wqkv_bf, DIM * DIM / 4);
  f32_to_bf16_kernel<<<DIM * DIM / 4 / 256, 256, 0, stream>>>(Wk, wqkv_bf + DIM * DIM, DIM * DIM / 4);
  f32_to_bf16_kernel<<<DIM * DIM / 4 / 256, 256, 0, stream>>>(Wv, wqkv_bf + 2 * DIM * DIM, DIM * DIM / 4);
  f32_to_bf16_kernel<<<DIM * DIM / 4 / 256, 256, 0, stream>>>(Wp, wp_bf, DIM * DIM / 4);
  f32_to_bf16_kernel<<<HIDDEN * DIM / 4 / 256, 256, 0, stream>>>(W1, w1_bf, HIDDEN * DIM / 4);
  f32_to_bf16_kernel<<<HIDDEN * DIM / 4 / 256, 256, 0, stream>>>(W2, w2_bf, HIDDEN * DIM / 4);

  // 2. h = LN1(x)
  ln_kernel<<<M_ROWS, 256, 0, stream>>>(x, g1, be1, h_bf);

  // 3. qkv = h @ [Wq;Wk;Wv]^T   (one GEMM, N = 3072)
  gemm_nt<EPI_BF16><<<dim3(73, 24), 256, 0, stream>>>(h_bf, DIM, wqkv_bf, DIM,
      qkv_bf, QKVLD, nullptr, nullptr, M_ROWS, 3 * DIM, DIM);

  // 4. vt[bh][d][n]
  transpose_v_kernel<<<256 * HEAD_DIM * (NPAD2 / 8) / 256, 256, 0, stream>>>(
      qkv_bf + 2 * DIM, vt_bf);

  // 5. fused flash attention -> o
  flash_attn_kernel<<<dim3(5, 256), 256, 0, stream>>>(
      qkv_bf, qkv_bf + DIM, vt_bf, o_bf);

  // 6. x1 = x + O @ Wp^T + bp   (x1 lives in d_out)
  gemm_nt<EPI_BIAS_RES_F32><<<dim3(73, 8), 256, 0, stream>>>(o_bf, DIM, wp_bf, DIM,
      x1, DIM, bp, x, M_ROWS, DIM, DIM);

  // 7. h2 = LN2(x1)
  ln_kernel<<<M_ROWS, 256, 0, stream>>>(x1, g2, be2, h2_bf);

  // 8. u = fast_gelu(h2 @ W1^T + b1)
  gemm_nt<EPI_BIAS_GELU_BF16><<<dim3(73, 32), 256, 0, stream>>>(h2_bf, DIM, w1_bf, DIM,
      u_bf, HIDDEN, b1, nullptr, M_ROWS, HIDDEN, DIM);

  // 9. out = x1 + u @ W2^T + b2
  gemm_nt<EPI_BIAS_RES_F32><<<dim3(73, 8), 256, 0, stream>>>(u_bf, HIDDEN, w2_bf, HIDDEN,
      out, DIM, b2, x1, M_ROWS, DIM, HIDDEN);
}

// Round 6
// 605.814 us; speedup vs baseline: 2.8922x; 1.1399x over previous
//
#include <hip/hip_runtime.h>

typedef short  short8  __attribute__((ext_vector_type(8)));
typedef float  float4v __attribute__((ext_vector_type(4)));

#define DIM      1024
#define HEADS    16
#define HEAD_DIM 64
#define HIDDEN   4096
#define BATCH    16
#define SEQ      577
#define M_ROWS   (BATCH*SEQ)   /* 9232 */
#define NPAD2    640           /* keys padded to 10*64 */
#define QKVLD    3072          /* merged qkv row stride */
#define LOG2E    1.4426950408889634f

static __device__ __forceinline__ unsigned short f2bf(float f) {
  unsigned int u = __float_as_uint(f);
  u += 0x7FFFu + ((u >> 16) & 1u);           // round-to-nearest-even
  return (unsigned short)(u >> 16);
}
static __device__ __forceinline__ float bf2f(unsigned short h) {
  return __uint_as_float(((unsigned int)h) << 16);
}
// async global->LDS, 16B per lane; LDS dest = wave-uniform base + lane*16
static __device__ __forceinline__ void gload_lds16(const void* g, void* l) {
  __builtin_amdgcn_global_load_lds(
      (const __attribute__((address_space(1))) void*)g,
      (__attribute__((address_space(3))) void*)l, 16, 0, 0);
}

// ---------------------------------------------------------------- fp32 -> bf16
__global__ __launch_bounds__(256) void f32_to_bf16_kernel(
    const float* __restrict__ in, unsigned short* __restrict__ out, int n4) {
  int i = blockIdx.x * 256 + threadIdx.x;
  if (i >= n4) return;
  float4 v = ((const float4*)in)[i];
  union { unsigned short s[4]; uint2 u; } p;
  p.s[0] = f2bf(v.x); p.s[1] = f2bf(v.y); p.s[2] = f2bf(v.z); p.s[3] = f2bf(v.w);
  ((uint2*)out)[i] = p.u;
}

// ---------------------------------------------------------------- LayerNorm row
__global__ __launch_bounds__(256) void ln_kernel(
    const float* __restrict__ x, const float* __restrict__ g,
    const float* __restrict__ b, unsigned short* __restrict__ out) {
  int row = blockIdx.x, tid = threadIdx.x;
  const float* xr = x + (long long)row * DIM;
  float4 v = *(const float4*)(xr + tid * 4);
  float s1 = v.x + v.y + v.z + v.w;
  float s2 = v.x*v.x + v.y*v.y + v.z*v.z + v.w*v.w;
  #pragma unroll
  for (int o = 32; o; o >>= 1) { s1 += __shfl_xor(s1, o); s2 += __shfl_xor(s2, o); }
  __shared__ float a1[4], a2[4];
  int wid = tid >> 6, lane = tid & 63;
  if (lane == 0) { a1[wid] = s1; a2[wid] = s2; }
  __syncthreads();
  s1 = a1[0] + a1[1] + a1[2] + a1[3];
  s2 = a2[0] + a2[1] + a2[2] + a2[3];
  float mean = s1 * (1.f / DIM);
  float var  = s2 * (1.f / DIM) - mean * mean;
  float rstd = rsqrtf(var + 1e-5f);
  float4 gv = *(const float4*)(g + tid * 4);
  float4 bv = *(const float4*)(b + tid * 4);
  union { unsigned short s[4]; uint2 u; } p;
  p.s[0] = f2bf((v.x - mean) * rstd * gv.x + bv.x);
  p.s[1] = f2bf((v.y - mean) * rstd * gv.y + bv.y);
  p.s[2] = f2bf((v.z - mean) * rstd * gv.z + bv.z);
  p.s[3] = f2bf((v.w - mean) * rstd * gv.w + bv.w);
  *(uint2*)(out + (long long)row * DIM + tid * 4) = p.u;
}

// ---------------------------------------------------------------- V transpose
__global__ __launch_bounds__(256) void transpose_v_kernel(
    const unsigned short* __restrict__ v, unsigned short* __restrict__ vt) {
  int t = blockIdx.x * 256 + threadIdx.x;          // exactly 256*64*80 threads
  int chunk = t % 80;
  int rest  = t / 80;
  int d  = rest & 63;
  int bh = rest >> 6;
  int b = bh >> 4, h = bh & 15;
  union { unsigned short s[8]; uint4 u; } p;
  #pragma unroll
  for (int i = 0; i < 8; i++) {
    int n = chunk * 8 + i;
    p.s[i] = (n < SEQ) ? v[((long long)(b * SEQ + n)) * QKVLD + h * HEAD_DIM + d] : (unsigned short)0;
  }
  *(uint4*)(vt + ((long long)bh * HEAD_DIM + d) * NPAD2 + chunk * 8) = p.u;
}

// ---------------------------------------------------------------- flash attention
// grid (5, 256): blockIdx.x = q-tile (128 rows), blockIdx.y = bh. (R5-verified)
__global__ __launch_bounds__(256, 2) void flash_attn_kernel(
    const unsigned short* __restrict__ q,   // qkv base + 0,    ld QKVLD
    const unsigned short* __restrict__ k,   // qkv base + 1024, ld QKVLD
    const unsigned short* __restrict__ vt,  // [bh][64][NPAD2]
    unsigned short* __restrict__ o) {       // [B*577][DIM]
  int qt = blockIdx.x;
  int bh = blockIdx.y;
  int b = bh >> 4, h = bh & 15;
  int q0 = qt * 128;
  int tid = threadIdx.x, lane = tid & 63, wid = tid >> 6;
  int quad = lane >> 4, l16 = lane & 15;
  long long rowbase = (long long)b * SEQ;

  __shared__ __align__(16) unsigned short SM[24576];   // 48 KB
  unsigned short* Qs = SM;            // [128][64]
  unsigned short* Ks = Qs + 128 * 64; // [64][64]
  unsigned short* Vs = Ks + 64 * 64;  // [64][64]  rows = d
  unsigned short* Ps = Vs + 64 * 64;  // [128][64]

  #pragma unroll
  for (int p = 0; p < 4; p++) {
    int r = wid * 32 + p * 8 + (lane >> 3);
    int c = lane & 7;
    int gr = q0 + r; if (gr > SEQ - 1) gr = SEQ - 1;
    gload_lds16(q + (rowbase + gr) * QKVLD + h * HEAD_DIM + ((c ^ (r & 7)) * 8),
                Qs + (wid * 32 + p * 8) * 64);
  }

  float mst[2][4], lst[2][4];
  float4v oacc[2][4];
  #pragma unroll
  for (int i = 0; i < 2; i++)
    #pragma unroll
    for (int r = 0; r < 4; r++) { mst[i][r] = -1e30f; lst[i][r] = 0.f; }
  #pragma unroll
  for (int i = 0; i < 2; i++)
    #pragma unroll
    for (int j = 0; j < 4; j++) oacc[i][j] = (float4v){0.f, 0.f, 0.f, 0.f};

  const float CE = 0.125f * LOG2E;

  for (int kt = 0; kt < 10; kt++) {
    if (kt) __syncthreads();
    #pragma unroll
    for (int p = 0; p < 2; p++) {
      int r = wid * 16 + p * 8 + (lane >> 3);
      int c = lane & 7;
      int gk = kt * 64 + r; if (gk > SEQ - 1) gk = SEQ - 1;
      gload_lds16(k + (rowbase + gk) * QKVLD + h * HEAD_DIM + ((c ^ (r & 7)) * 8),
                  Ks + (wid * 16 + p * 8) * 64);
      gload_lds16(vt + ((long long)bh * HEAD_DIM + r) * NPAD2 + kt * 64 + ((c ^ (r & 7)) * 8),
                  Vs + (wid * 16 + p * 8) * 64);
    }
    __syncthreads();

    float4v sacc[2][4];
    #pragma unroll
    for (int i = 0; i < 2; i++)
      #pragma unroll
      for (int j = 0; j < 4; j++) sacc[i][j] = (float4v){0.f, 0.f, 0.f, 0.f};
    short8 af[2][2], bfr[4][2];
    #pragma unroll
    for (int i = 0; i < 2; i++) {
      int r = wid * 32 + i * 16 + l16;
      #pragma unroll
      for (int ks = 0; ks < 2; ks++)
        af[i][ks] = *(const short8*)(Qs + r * 64 + ((ks * 4 + quad) ^ (l16 & 7)) * 8);
    }
    #pragma unroll
    for (int j = 0; j < 4; j++) {
      int r = j * 16 + l16;
      #pragma unroll
      for (int ks = 0; ks < 2; ks++)
        bfr[j][ks] = *(const short8*)(Ks + r * 64 + ((ks * 4 + quad) ^ (l16 & 7)) * 8);
    }
    #pragma unroll
    for (int i = 0; i < 2; i++)
      #pragma unroll
      for (int j = 0; j < 4; j++)
        #pragma unroll
        for (int ks = 0; ks < 2; ks++)
          sacc[i][j] = __builtin_amdgcn_mfma_f32_16x16x32_bf16(af[i][ks], bfr[j][ks], sacc[i][j], 0, 0, 0);

    #pragma unroll
    for (int i = 0; i < 2; i++) {
      #pragma unroll
      for (int reg = 0; reg < 4; reg++) {
        float mx = -1e30f;
        #pragma unroll
        for (int j = 0; j < 4; j++) {
          int col = kt * 64 + j * 16 + l16;
          float s = (col < SEQ) ? sacc[i][j][reg] : -1e30f;
          mx = fmaxf(mx, s);
        }
        mx = fmaxf(mx, __shfl_xor(mx, 1));
        mx = fmaxf(mx, __shfl_xor(mx, 2));
        mx = fmaxf(mx, __shfl_xor(mx, 4));
        mx = fmaxf(mx, __shfl_xor(mx, 8));
        float mnew  = fmaxf(mst[i][reg], mx);
        float alpha = __builtin_amdgcn_exp2f((mst[i][reg] - mnew) * CE);
        mst[i][reg] = mnew;
        int prow = wid * 32 + i * 16 + quad * 4 + reg;
        float rs = 0.f;
        #pragma unroll
        for (int j = 0; j < 4; j++) {
          int col = kt * 64 + j * 16 + l16;
          float pv = (col < SEQ) ? __builtin_amdgcn_exp2f((sacc[i][j][reg] - mnew) * CE) : 0.f;
          rs += pv;
          int pcol = j * 16 + l16;
          Ps[prow * 64 + (((pcol >> 3) ^ (prow & 7)) * 8) + (pcol & 7)] = f2bf(pv);
        }
        rs += __shfl_xor(rs, 1); rs += __shfl_xor(rs, 2);
        rs += __shfl_xor(rs, 4); rs += __shfl_xor(rs, 8);
        lst[i][reg] = lst[i][reg] * alpha + rs;
        #pragma unroll
        for (int j = 0; j < 4; j++) oacc[i][j][reg] *= alpha;
      }
    }

    short8 paf[2][2], vbf[4][2];
    #pragma unroll
    for (int i = 0; i < 2; i++) {
      int r = wid * 32 + i * 16 + l16;
      #pragma unroll
      for (int kk = 0; kk < 2; kk++)
        paf[i][kk] = *(const short8*)(Ps + r * 64 + ((kk * 4 + quad) ^ (l16 & 7)) * 8);
    }
    #pragma unroll
    for (int j = 0; j < 4; j++) {
      int r = j * 16 + l16;
      #pragma unroll
      for (int kk = 0; kk < 2; kk++)
        vbf[j][kk] = *(const short8*)(Vs + r * 64 + ((kk * 4 + quad) ^ (l16 & 7)) * 8);
    }
    #pragma unroll
    for (int i = 0; i < 2; i++)
      #pragma unroll
      for (int j = 0; j < 4; j++)
        #pragma unroll
        for (int kk = 0; kk < 2; kk++)
          oacc[i][j] = __builtin_amdgcn_mfma_f32_16x16x32_bf16(paf[i][kk], vbf[j][kk], oacc[i][j], 0, 0, 0);
  }

  #pragma unroll
  for (int i = 0; i < 2; i++) {
    #pragma unroll
    for (int reg = 0; reg < 4; reg++) {
      int grow = q0 + wid * 32 + i * 16 + quad * 4 + reg;
      if (grow >= SEQ) continue;
      float inv = 1.f / lst[i][reg];
      #pragma unroll
      for (int j = 0; j < 4; j++) {
        int d = j * 16 + l16;
        o[(rowbase + grow) * DIM + h * HEAD_DIM + d] = f2bf(oacc[i][j][reg] * inv);
      }
    }
  }
}

// ---------------------------------------------------------------- NT GEMM
// C[M,N] = A[M,K] x B[N,K]^T (both row-major bf16). Block 128x128, 4 waves
// 2x2, wave 64x64 via 4x4 mfma 16x16x32. R6: (a) flat-id swizzle into bands
// of 8 M-tiles, m-fastest, for L2 A/W reuse; (b) BK=64 (one barrier pair per
// 64 K, two ks-slices); (c) XOR-chunk-swizzled LDS -> conflict-free
// ds_read_b128. LDS-slab epilogue (anti-spill, R3-verified).
enum { EPI_BF16 = 0, EPI_BIAS_RES_F32 = 2, EPI_BIAS_GELU_BF16 = 3 };

template <int EPI>
__global__ __launch_bounds__(256, 2) void gemm_nt(
    const unsigned short* __restrict__ A, int lda,
    const unsigned short* __restrict__ B, int ldb,
    void* __restrict__ Cout, int ldc,
    const float* __restrict__ bias, const float* __restrict__ res,
    int M, int N, int K) {
  // ---- band swizzle: bands of 8 m-tiles, m fastest within band ----
  int mt = gridDim.x, nt = gridDim.y;
  int id = blockIdx.y * mt + blockIdx.x;
  int band  = id / (8 * nt);
  int rem   = id - band * 8 * nt;
  int mrem  = mt - band * 8;
  int bandh = mrem < 8 ? mrem : 8;     // only the last band is short
  int lm = rem % bandh;
  int nb = rem / bandh;
  int m0 = (band * 8 + lm) * 128, n0 = nb * 128;

  int tid = threadIdx.x;
  int lane = tid & 63, wid = tid >> 6;
  int wm = wid >> 1, wn = wid & 1;
  int quad = lane >> 4, l16 = lane & 15;

  // K-loop: As[128][64] + Bs[128][64] = 32768 B; epilogue slab 17408 B reuses it
  __shared__ __align__(16) char SMEM[32768];
  unsigned short* As = (unsigned short*)SMEM;        // XOR-chunk swizzled
  unsigned short* Bs = As + 128 * 64;

  float4v acc[4][4];
  #pragma unroll
  for (int i = 0; i < 4; i++)
    #pragma unroll
    for (int j = 0; j < 4; j++) acc[i][j] = (float4v){0.f, 0.f, 0.f, 0.f};

  int lr8 = lane >> 3;          // 0..7 row within 8-row group
  int lc8 = lane & 7;           // 16B chunk within 128B row
  int sc  = (lc8 ^ lr8) * 8;    // swizzled source chunk (elements)

  for (int k0 = 0; k0 < K; k0 += 64) {
    #pragma unroll
    for (int p = 0; p < 4; p++) {
      int ra = wid * 32 + p * 8;                     // wave-uniform row base
      int gr = m0 + ra + lr8; if (gr > M - 1) gr = M - 1;
      gload_lds16(A + (long long)gr * lda + k0 + sc, As + ra * 64);
      int gn = n0 + ra + lr8; if (gn > N - 1) gn = N - 1;
      gload_lds16(B + (long long)gn * ldb + k0 + sc, Bs + ra * 64);
    }
    __syncthreads();
    #pragma unroll
    for (int ks = 0; ks < 2; ks++) {
      short8 af[4], bfr[4];
      #pragma unroll
      for (int i = 0; i < 4; i++)
        af[i]  = *(const short8*)(As + (wm * 64 + i * 16 + l16) * 64 + (((ks * 4 + quad) ^ (l16 & 7)) * 8));
      #pragma unroll
      for (int j = 0; j < 4; j++)
        bfr[j] = *(const short8*)(Bs + (wn * 64 + j * 16 + l16) * 64 + (((ks * 4 + quad) ^ (l16 & 7)) * 8));
      #pragma unroll
      for (int i = 0; i < 4; i++)
        #pragma unroll
        for (int j = 0; j < 4; j++)
          acc[i][j] = __builtin_amdgcn_mfma_f32_16x16x32_bf16(af[i], bfr[j], acc[i][j], 0, 0, 0);
    }
    __syncthreads();
  }

  // -------- epilogue via LDS (per-wave 16x64 fp32 slab, row stride 68) -----
  float* cs = (float*)SMEM + wid * (16 * 68);
  int erow = lane >> 2;
  int eq   = lane & 3;

  #pragma unroll
  for (int i = 0; i < 4; i++) {
    #pragma unroll
    for (int j = 0; j < 4; j++)
      #pragma unroll
      for (int r = 0; r < 4; r++)
        cs[(quad * 4 + r) * 68 + j * 16 + l16] = acc[i][j][r];
    int grow = m0 + wm * 64 + i * 16 + erow;
    bool rowok = grow < M;

    if constexpr (EPI == EPI_BIAS_RES_F32) {
      #pragma unroll
      for (int t = 0; t < 4; t++) {
        int colb = t * 16 + eq * 4;
        int gcol = n0 + wn * 64 + colb;
        if (!rowok || gcol >= N) continue;
        float4 vv = *(const float4*)&cs[erow * 68 + colb];
        float4 bb = *(const float4*)&bias[gcol];
        const float4 rr = *(const float4*)&res[(long long)grow * ldc + gcol];
        vv.x += bb.x + rr.x; vv.y += bb.y + rr.y;
        vv.z += bb.z + rr.z; vv.w += bb.w + rr.w;
        *(float4*)((float*)Cout + (long long)grow * ldc + gcol) = vv;
      }
    } else {
      #pragma unroll
      for (int h = 0; h < 2; h++) {
        int colb = h * 32 + eq * 8;
        int gcol = n0 + wn * 64 + colb;
        if (!rowok || gcol >= N) continue;
        float4 a0 = *(const float4*)&cs[erow * 68 + colb];
        float4 a1 = *(const float4*)&cs[erow * 68 + colb + 4];
        float vs[8] = {a0.x, a0.y, a0.z, a0.w, a1.x, a1.y, a1.z, a1.w};
        if constexpr (EPI == EPI_BIAS_GELU_BF16) {
          float4 b0 = *(const float4*)&bias[gcol];
          float4 b1 = *(const float4*)&bias[gcol + 4];
          float bs[8] = {b0.x, b0.y, b0.z, b0.w, b1.x, b1.y, b1.z, b1.w};
          #pragma unroll
          for (int e = 0; e < 8; e++) {
            float tt = vs[e] + bs[e];
            float ex = __builtin_amdgcn_exp2f(tt * -2.4554669595930156f);
            vs[e] = tt / (1.f + ex);
          }
        }
        union { unsigned short s[8]; uint4 u; } p;
        #pragma unroll
        for (int e = 0; e < 8; e++) p.s[e] = f2bf(vs[e]);
        *(uint4*)((unsigned short*)Cout + (long long)grow * ldc + gcol) = p.u;
      }
    }
  }
}

// ----------------------------------------------------------------------------
extern "C" void kernel_launch(void* const* d_in, const int* in_sizes, int n_in,
                              void* d_out, int out_size, void* d_ws, size_t ws_size,
                              hipStream_t stream) {
  const float* x   = (const float*)d_in[0];
  const float* g1  = (const float*)d_in[1];
  const float* be1 = (const float*)d_in[2];
  const float* Wq  = (const float*)d_in[3];
  const float* Wk  = (const float*)d_in[4];
  const float* Wv  = (const float*)d_in[5];
  const float* Wp  = (const float*)d_in[6];
  const float* bp  = (const float*)d_in[7];
  const float* g2  = (const float*)d_in[8];
  const float* be2 = (const float*)d_in[9];
  const float* W1  = (const float*)d_in[10];
  const float* b1  = (const float*)d_in[11];
  const float* W2  = (const float*)d_in[12];
  const float* b2  = (const float*)d_in[13];
  float* out = (float*)d_out;

  char* ws = (char*)d_ws;
  size_t off = 0;
  auto alloc = [&](size_t bytes) {
    size_t r = off; off += (bytes + 255) & ~(size_t)255; return r;
  };
  unsigned short* wqkv_bf = (unsigned short*)(ws + alloc((size_t)3 * DIM * DIM * 2)); // [Wq;Wk;Wv]
  unsigned short* wp_bf   = (unsigned short*)(ws + alloc((size_t)DIM * DIM * 2));
  unsigned short* w1_bf   = (unsigned short*)(ws + alloc((size_t)HIDDEN * DIM * 2));
  unsigned short* w2_bf   = (unsigned short*)(ws + alloc((size_t)HIDDEN * DIM * 2));
  unsigned short* h_bf    = (unsigned short*)(ws + alloc((size_t)M_ROWS * DIM * 2));  // ln1; later o; later ln2
  unsigned short* qkv_bf  = (unsigned short*)(ws + alloc((size_t)M_ROWS * QKVLD * 2));
  unsigned short* vt_bf   = (unsigned short*)(ws + alloc((size_t)256 * HEAD_DIM * NPAD2 * 2));

  unsigned short* o_bf  = h_bf;     // o written after ln1-out dead
  unsigned short* h2_bf = h_bf;     // ln2-out after o consumed
  unsigned short* u_bf  = qkv_bf;   // MLP hidden (75.6 MB) over dead [qkv|vt] span
  float*          x1    = out;      // residual-1 lives in d_out

  // 1. weights fp32 -> bf16
  f32_to_bf16_kernel<<<DIM * DIM / 4 / 256, 256, 0, stream>>>(Wq, wqkv_bf, DIM * DIM / 4);
  f32_to_bf16_kernel<<<DIM * DIM / 4 / 256, 256, 0, stream>>>(Wk, wqkv_bf + DIM * DIM, DIM * DIM / 4);
  f32_to_bf16_kernel<<<DIM * DIM / 4 / 256, 256, 0, stream>>>(Wv, wqkv_bf + 2 * DIM * DIM, DIM * DIM / 4);
  f32_to_bf16_kernel<<<DIM * DIM / 4 / 256, 256, 0, stream>>>(Wp, wp_bf, DIM * DIM / 4);
  f32_to_bf16_kernel<<<HIDDEN * DIM / 4 / 256, 256, 0, stream>>>(W1, w1_bf, HIDDEN * DIM / 4);
  f32_to_bf16_kernel<<<HIDDEN * DIM / 4 / 256, 256, 0, stream>>>(W2, w2_bf, HIDDEN * DIM / 4);

  // 2. h = LN1(x)
  ln_kernel<<<M_ROWS, 256, 0, stream>>>(x, g1, be1, h_bf);

  // 3. qkv = h @ [Wq;Wk;Wv]^T   (one GEMM, N = 3072)
  gemm_nt<EPI_BF16><<<dim3(73, 24), 256, 0, stream>>>(h_bf, DIM, wqkv_bf, DIM,
      qkv_bf, QKVLD, nullptr, nullptr, M_ROWS, 3 * DIM, DIM);

  // 4. vt[bh][d][n]
  transpose_v_kernel<<<256 * HEAD_DIM * (NPAD2 / 8) / 256, 256, 0, stream>>>(
      qkv_bf + 2 * DIM, vt_bf);

  // 5. fused flash attention -> o
  flash_attn_kernel<<<dim3(5, 256), 256, 0, stream>>>(
      qkv_bf, qkv_bf + DIM, vt_bf, o_bf);

  // 6. x1 = x + O @ Wp^T + bp   (x1 lives in d_out)
  gemm_nt<EPI_BIAS_RES_F32><<<dim3(73, 8), 256, 0, stream>>>(o_bf, DIM, wp_bf, DIM,
      x1, DIM, bp, x, M_ROWS, DIM, DIM);

  // 7. h2 = LN2(x1)
  ln_kernel<<<M_ROWS, 256, 0, stream>>>(x1, g2, be2, h2_bf);

  // 8. u = fast_gelu(h2 @ W1^T + b1)
  gemm_nt<EPI_BIAS_GELU_BF16><<<dim3(73, 32), 256, 0, stream>>>(h2_bf, DIM, w1_bf, DIM,
      u_bf, HIDDEN, b1, nullptr, M_ROWS, HIDDEN, DIM);

  // 9. out = x1 + u @ W2^T + b2
  gemm_nt<EPI_BIAS_RES_F32><<<dim3(73, 8), 256, 0, stream>>>(u_bf, HIDDEN, w2_bf, HIDDEN,
      out, DIM, b2, x1, M_ROWS, DIM, HIDDEN);
}